// Round 1
// baseline (566.898 us; speedup 1.0000x reference)
//
#include <hip/hip_runtime.h>

#define BS 2
#define HR 1024
#define WR 1024

static inline int cdiv(int a, int b) { return (a + b - 1) / b; }

// Generic 3x3 conv, pad=1, arbitrary stride, optional bias/relu. NCHW / OIHW.
__global__ void conv3x3_kernel(const float* __restrict__ in, const float* __restrict__ w,
                               const float* __restrict__ bias, float* __restrict__ out,
                               int Cin, int Cout, int Hin, int Win, int Hout, int Wout,
                               int stride, int do_relu) {
    int idx = blockIdx.x * blockDim.x + threadIdx.x;
    int total = BS * Cout * Hout * Wout;
    if (idx >= total) return;
    int ox = idx % Wout;
    int oy = (idx / Wout) % Hout;
    int oc = (idx / (Wout * Hout)) % Cout;
    int b  = idx / (Wout * Hout * Cout);

    float acc = bias ? bias[oc] : 0.0f;
    const float* wp = w + (size_t)oc * Cin * 9;
    const float* ip = in + (size_t)b * Cin * Hin * Win;
    int iy0 = oy * stride - 1;
    int ix0 = ox * stride - 1;
    for (int ic = 0; ic < Cin; ++ic) {
        const float* ipc = ip + (size_t)ic * Hin * Win;
        const float* wpc = wp + ic * 9;
#pragma unroll
        for (int ky = 0; ky < 3; ++ky) {
            int iy = iy0 + ky;
            if (iy < 0 || iy >= Hin) continue;
#pragma unroll
            for (int kx = 0; kx < 3; ++kx) {
                int ix = ix0 + kx;
                if (ix < 0 || ix >= Win) continue;
                acc += wpc[ky * 3 + kx] * ipc[iy * Win + ix];
            }
        }
    }
    if (do_relu) acc = fmaxf(acc, 0.0f);
    out[idx] = acc;
}

// Fully-connected: out[b][o] = (relu)(bias[o] + sum_i w[o][i]*in[b][i])
__global__ void fc_kernel(const float* __restrict__ in, const float* __restrict__ w,
                          const float* __restrict__ bias, float* __restrict__ out,
                          int In, int Out, int do_relu) {
    int idx = blockIdx.x * blockDim.x + threadIdx.x;
    if (idx >= BS * Out) return;
    int o = idx % Out;
    int b = idx / Out;
    const float* ip = in + (size_t)b * In;
    const float* wp = w + (size_t)o * In;
    float acc = bias[o];
    for (int i = 0; i < In; ++i) acc += wp[i] * ip[i];
    if (do_relu) acc = fmaxf(acc, 0.0f);
    out[idx] = acc;
}

// fusion = relu(gf[b,ic] + lf[b,ic,y,x]); grid = 1x1 conv(pred_w,pred_b) -> (BS,96,16,16)
__global__ void fuse_pred_kernel(const float* __restrict__ lf, const float* __restrict__ gfv,
                                 const float* __restrict__ pw, const float* __restrict__ pb,
                                 float* __restrict__ grid) {
    int idx = blockIdx.x * blockDim.x + threadIdx.x;
    int total = BS * 96 * 256;
    if (idx >= total) return;
    int sp = idx % 256;
    int oc = (idx / 256) % 96;
    int b  = idx / (256 * 96);
    float acc = pb[oc];
    const float* lfp = lf + (size_t)b * 64 * 256;
    const float* gp  = gfv + (size_t)b * 64;
    const float* wp  = pw + oc * 64;
    for (int ic = 0; ic < 64; ++ic) {
        float f = fmaxf(gp[ic] + lfp[ic * 256 + sp], 0.0f);
        acc += wp[ic] * f;
    }
    grid[idx] = acc;
}

// Per-pixel: guide curve + trilinear bilateral-grid slice + affine assembly.
__global__ void slice_kernel(const float* __restrict__ hr, const float* __restrict__ grid,
                             const float* __restrict__ pw_mat, const float* __restrict__ pw_bias,
                             const float* __restrict__ pw_bias_tag,
                             const float* __restrict__ rho_a, const float* __restrict__ rho_t,
                             float* __restrict__ out) {
    __shared__ float s_rt[48], s_ra[48], s_m[9], s_bt[3], s_pb;
    int t = threadIdx.x;
    if (t < 48) { s_rt[t] = rho_t[t]; s_ra[t] = rho_a[t]; }
    if (t < 9)  s_m[t] = pw_mat[t];
    if (t < 3)  s_bt[t] = pw_bias_tag[t];
    if (t == 0) s_pb = pw_bias[0];
    __syncthreads();

    int idx = blockIdx.x * blockDim.x + t;
    int total = BS * HR * WR;
    if (idx >= total) return;
    int x = idx % WR;
    int y = (idx / WR) % HR;
    int b = idx / (WR * HR);

    const size_t plane = (size_t)HR * WR;
    const float* hp = hr + (size_t)b * 3 * plane + (size_t)y * WR + x;
    float r  = hp[0];
    float g  = hp[plane];
    float bl = hp[2 * plane];

    // guide
    float g0 = s_m[0] * r + s_m[1] * g + s_m[2] * bl + s_bt[0];
    float g1 = s_m[3] * r + s_m[4] * g + s_m[5] * bl + s_bt[1];
    float g2 = s_m[6] * r + s_m[7] * g + s_m[8] * bl + s_bt[2];
    float guide = s_pb;
#pragma unroll
    for (int k = 0; k < 16; ++k) {
        guide += fmaxf(g0 - s_rt[k * 3 + 0], 0.0f) * s_ra[k * 3 + 0];
        guide += fmaxf(g1 - s_rt[k * 3 + 1], 0.0f) * s_ra[k * 3 + 1];
        guide += fmaxf(g2 - s_rt[k * 3 + 2], 0.0f) * s_ra[k * 3 + 2];
    }

    // grid coordinates (GD=8, GH=16, GW=16)
    float gx = (x + 0.5f) * (16.0f / WR);
    float gy = (y + 0.5f) * (16.0f / HR);
    float gz = fminf(fmaxf(guide, 0.0f), 1.0f) * 8.0f;
    float fxf = fmaxf(floorf(gx - 0.5f), 0.0f);
    float fyf = fmaxf(floorf(gy - 0.5f), 0.0f);
    float fzf = fmaxf(floorf(gz - 0.5f), 0.0f);
    float wx = gx - 0.5f - fxf;           // keeps sign (torch semantics)
    float wy = gy - 0.5f - fyf;           // keeps sign
    float wz = fabsf(gz - 0.5f - fzf);    // abs (torch semantics)
    int fx = (int)fxf; int cx = min(fx + 1, 15);
    int fy = (int)fyf; int cy = min(fy + 1, 15);
    int fz = (int)fzf; int cz = min(fz + 1, 7);

    const float* gp2 = grid + (size_t)b * 12 * 2048;
    int l_fff = fz * 256 + fy * 16 + fx;
    int l_cff = cz * 256 + fy * 16 + fx;
    int l_fcf = fz * 256 + cy * 16 + fx;
    int l_ccf = cz * 256 + cy * 16 + fx;
    int l_ffc = fz * 256 + fy * 16 + cx;
    int l_cfc = cz * 256 + fy * 16 + cx;
    int l_fcc = fz * 256 + cy * 16 + cx;
    int l_ccc = cz * 256 + cy * 16 + cx;

    float ex = 1.0f - wx, ey = 1.0f - wy, ez = 1.0f - wz;
    float w_fff = ex * ey * ez;
    float w_cff = ex * ey * wz;
    float w_fcf = ex * wy * ez;
    float w_ccf = ex * wy * wz;
    float w_ffc = wx * ey * ez;
    float w_cfc = wx * ey * wz;
    float w_fcc = wx * wy * ez;
    float w_ccc = wx * wy * wz;

    float a[12];
#pragma unroll
    for (int ch = 0; ch < 12; ++ch) {
        const float* gc = gp2 + ch * 2048;
        a[ch] = gc[l_fff] * w_fff + gc[l_cff] * w_cff
              + gc[l_fcf] * w_fcf + gc[l_ccf] * w_ccf
              + gc[l_ffc] * w_ffc + gc[l_cfc] * w_cfc
              + gc[l_fcc] * w_fcc + gc[l_ccc] * w_ccc;
    }

    size_t ob = (size_t)b * 3 * plane + (size_t)y * WR + x;
    out[ob]             = a[0] * r + a[1]  * g + a[2]  * bl + a[3];
    out[ob + plane]     = a[4] * r + a[5]  * g + a[6]  * bl + a[7];
    out[ob + 2 * plane] = a[8] * r + a[9]  * g + a[10] * bl + a[11];
}

extern "C" void kernel_launch(void* const* d_in, const int* in_sizes, int n_in,
                              void* d_out, int out_size, void* d_ws, size_t ws_size,
                              hipStream_t stream) {
    const float* high_res   = (const float*)d_in[0];
    const float* low_res    = (const float*)d_in[1];
    const float* ll1_w = (const float*)d_in[2];  const float* ll1_b = (const float*)d_in[3];
    const float* ll2_w = (const float*)d_in[4];  const float* ll2_b = (const float*)d_in[5];
    const float* ll3_w = (const float*)d_in[6];  const float* ll3_b = (const float*)d_in[7];
    const float* ll4_w = (const float*)d_in[8];  const float* ll4_b = (const float*)d_in[9];
    const float* lf1_w = (const float*)d_in[10]; const float* lf1_b = (const float*)d_in[11];
    const float* lf2_w = (const float*)d_in[12];
    const float* gf1_w = (const float*)d_in[13]; const float* gf1_b = (const float*)d_in[14];
    const float* gf2_w = (const float*)d_in[15]; const float* gf2_b = (const float*)d_in[16];
    const float* fc1_w = (const float*)d_in[17]; const float* fc1_b = (const float*)d_in[18];
    const float* fc2_w = (const float*)d_in[19]; const float* fc2_b = (const float*)d_in[20];
    const float* fc3_w = (const float*)d_in[21]; const float* fc3_b = (const float*)d_in[22];
    const float* pred_w = (const float*)d_in[23]; const float* pred_b = (const float*)d_in[24];
    const float* pw_mat = (const float*)d_in[25];
    const float* pw_bias = (const float*)d_in[26];
    const float* pw_bias_tag = (const float*)d_in[27];
    const float* rho_a = (const float*)d_in[28];
    const float* rho_t = (const float*)d_in[29];

    float* ws = (float*)d_ws;
    // workspace layout (floats)
    float* b1   = ws;                 // (2,8,128,128)  262144
    float* b2   = b1 + 262144;        // (2,16,64,64)   131072
    float* b3   = b2 + 131072;        // (2,32,32,32)    65536
    float* b4   = b3 + 65536;         // (2,64,16,16)    32768
    float* lf1o = b4 + 32768;         // (2,64,16,16)    32768
    float* lf2o = lf1o + 32768;       // (2,64,16,16)    32768
    float* gf1o = lf2o + 32768;       // (2,64,8,8)       8192
    float* gf2o = gf1o + 8192;        // (2,64,4,4)       2048
    float* fc1o = gf2o + 2048;        // (2,256)           512
    float* fc2o = fc1o + 512;         // (2,128)           256
    float* fc3o = fc2o + 256;         // (2,64)            128
    float* grid = fc3o + 128;         // (2,96,16,16)    49152

    float* out = (float*)d_out;
    dim3 blk(256);

    // low-res CNN
    conv3x3_kernel<<<cdiv(BS*8*128*128, 256),  blk, 0, stream>>>(low_res, ll1_w, ll1_b, b1, 3, 8, 256, 256, 128, 128, 2, 1);
    conv3x3_kernel<<<cdiv(BS*16*64*64, 256),   blk, 0, stream>>>(b1, ll2_w, ll2_b, b2, 8, 16, 128, 128, 64, 64, 2, 1);
    conv3x3_kernel<<<cdiv(BS*32*32*32, 256),   blk, 0, stream>>>(b2, ll3_w, ll3_b, b3, 16, 32, 64, 64, 32, 32, 2, 1);
    conv3x3_kernel<<<cdiv(BS*64*16*16, 256),   blk, 0, stream>>>(b3, ll4_w, ll4_b, b4, 32, 64, 32, 32, 16, 16, 2, 1);
    // local features
    conv3x3_kernel<<<cdiv(BS*64*16*16, 256),   blk, 0, stream>>>(b4, lf1_w, lf1_b, lf1o, 64, 64, 16, 16, 16, 16, 1, 1);
    conv3x3_kernel<<<cdiv(BS*64*16*16, 256),   blk, 0, stream>>>(lf1o, lf2_w, nullptr, lf2o, 64, 64, 16, 16, 16, 16, 1, 0);
    // global features
    conv3x3_kernel<<<cdiv(BS*64*8*8, 256),     blk, 0, stream>>>(b4, gf1_w, gf1_b, gf1o, 64, 64, 16, 16, 8, 8, 2, 1);
    conv3x3_kernel<<<cdiv(BS*64*4*4, 256),     blk, 0, stream>>>(gf1o, gf2_w, gf2_b, gf2o, 64, 64, 8, 8, 4, 4, 2, 1);
    fc_kernel<<<cdiv(BS*256, 256), blk, 0, stream>>>(gf2o, fc1_w, fc1_b, fc1o, 1024, 256, 1);
    fc_kernel<<<cdiv(BS*128, 256), blk, 0, stream>>>(fc1o, fc2_w, fc2_b, fc2o, 256, 128, 1);
    fc_kernel<<<cdiv(BS*64, 256),  blk, 0, stream>>>(fc2o, fc3_w, fc3_b, fc3o, 128, 64, 0);
    // fusion + pred (bilateral grid)
    fuse_pred_kernel<<<cdiv(BS*96*256, 256), blk, 0, stream>>>(lf2o, fc3o, pred_w, pred_b, grid);
    // per-pixel guide + slice + assemble
    slice_kernel<<<cdiv(BS*HR*WR, 256), blk, 0, stream>>>(high_res, grid, pw_mat, pw_bias, pw_bias_tag,
                                                          rho_a, rho_t, out);
}

// Round 2
// 393.886 us; speedup vs baseline: 1.4392x; 1.4392x over previous
//
#include <hip/hip_runtime.h>

#define BS 2
#define HR 1024
#define WR 1024

static inline int cdiv(int a, int b) { return (a + b - 1) / b; }

// Generic 3x3 conv, pad=1, arbitrary stride, optional bias/relu. NCHW / OIHW.
__global__ void conv3x3_kernel(const float* __restrict__ in, const float* __restrict__ w,
                               const float* __restrict__ bias, float* __restrict__ out,
                               int Cin, int Cout, int Hin, int Win, int Hout, int Wout,
                               int stride, int do_relu) {
    int idx = blockIdx.x * blockDim.x + threadIdx.x;
    int total = BS * Cout * Hout * Wout;
    if (idx >= total) return;
    int ox = idx % Wout;
    int oy = (idx / Wout) % Hout;
    int oc = (idx / (Wout * Hout)) % Cout;
    int b  = idx / (Wout * Hout * Cout);

    float acc = bias ? bias[oc] : 0.0f;
    const float* wp = w + (size_t)oc * Cin * 9;
    const float* ip = in + (size_t)b * Cin * Hin * Win;
    int iy0 = oy * stride - 1;
    int ix0 = ox * stride - 1;
    for (int ic = 0; ic < Cin; ++ic) {
        const float* ipc = ip + (size_t)ic * Hin * Win;
        const float* wpc = wp + ic * 9;
#pragma unroll
        for (int ky = 0; ky < 3; ++ky) {
            int iy = iy0 + ky;
            if (iy < 0 || iy >= Hin) continue;
#pragma unroll
            for (int kx = 0; kx < 3; ++kx) {
                int ix = ix0 + kx;
                if (ix < 0 || ix >= Win) continue;
                acc += wpc[ky * 3 + kx] * ipc[iy * Win + ix];
            }
        }
    }
    if (do_relu) acc = fmaxf(acc, 0.0f);
    out[idx] = acc;
}

// Fully-connected, one 64-lane wave per output neuron.
// out[b][o] = (relu)(bias[o] + sum_i w[o][i]*in[b][i])
__global__ void fc_wave_kernel(const float* __restrict__ in, const float* __restrict__ w,
                               const float* __restrict__ bias, float* __restrict__ out,
                               int In, int Out, int do_relu) {
    int wid  = (blockIdx.x * blockDim.x + threadIdx.x) >> 6;
    int lane = threadIdx.x & 63;
    if (wid >= BS * Out) return;
    int o = wid % Out;
    int b = wid / Out;
    const float* ip = in + (size_t)b * In;
    const float* wp = w + (size_t)o * In;

    float acc = 0.0f;
    // In is a multiple of 4 for all layers here (1024, 256, 128)
    for (int i = lane * 4; i < In; i += 64 * 4) {
        float4 wv = *reinterpret_cast<const float4*>(wp + i);
        float4 iv = *reinterpret_cast<const float4*>(ip + i);
        acc += wv.x * iv.x + wv.y * iv.y + wv.z * iv.z + wv.w * iv.w;
    }
#pragma unroll
    for (int off = 32; off > 0; off >>= 1) acc += __shfl_xor(acc, off, 64);
    if (lane == 0) {
        acc += bias[o];
        if (do_relu) acc = fmaxf(acc, 0.0f);
        out[(size_t)b * Out + o] = acc;
    }
}

// fusion = relu(gf[b,ic] + lf[b,ic,y,x]); grid = 1x1 conv(pred_w,pred_b) -> (BS,96,16,16)
__global__ void fuse_pred_kernel(const float* __restrict__ lf, const float* __restrict__ gfv,
                                 const float* __restrict__ pw, const float* __restrict__ pb,
                                 float* __restrict__ grid) {
    int idx = blockIdx.x * blockDim.x + threadIdx.x;
    int total = BS * 96 * 256;
    if (idx >= total) return;
    int sp = idx % 256;
    int oc = (idx / 256) % 96;
    int b  = idx / (256 * 96);
    float acc = pb[oc];
    const float* lfp = lf + (size_t)b * 64 * 256;
    const float* gp  = gfv + (size_t)b * 64;
    const float* wp  = pw + oc * 64;
    for (int ic = 0; ic < 64; ++ic) {
        float f = fmaxf(gp[ic] + lfp[ic * 256 + sp], 0.0f);
        acc += wp[ic] * f;
    }
    grid[idx] = acc;
}

// Per-pixel: guide curve + trilinear bilateral-grid slice + affine assembly.
__global__ void slice_kernel(const float* __restrict__ hr, const float* __restrict__ grid,
                             const float* __restrict__ pw_mat, const float* __restrict__ pw_bias,
                             const float* __restrict__ pw_bias_tag,
                             const float* __restrict__ rho_a, const float* __restrict__ rho_t,
                             float* __restrict__ out) {
    __shared__ float s_rt[48], s_ra[48], s_m[9], s_bt[3], s_pb;
    int t = threadIdx.x;
    if (t < 48) { s_rt[t] = rho_t[t]; s_ra[t] = rho_a[t]; }
    if (t < 9)  s_m[t] = pw_mat[t];
    if (t < 3)  s_bt[t] = pw_bias_tag[t];
    if (t == 0) s_pb = pw_bias[0];
    __syncthreads();

    int idx = blockIdx.x * blockDim.x + t;
    int total = BS * HR * WR;
    if (idx >= total) return;
    int x = idx % WR;
    int y = (idx / WR) % HR;
    int b = idx / (WR * HR);

    const size_t plane = (size_t)HR * WR;
    const float* hp = hr + (size_t)b * 3 * plane + (size_t)y * WR + x;
    float r  = hp[0];
    float g  = hp[plane];
    float bl = hp[2 * plane];

    // guide
    float g0 = s_m[0] * r + s_m[1] * g + s_m[2] * bl + s_bt[0];
    float g1 = s_m[3] * r + s_m[4] * g + s_m[5] * bl + s_bt[1];
    float g2 = s_m[6] * r + s_m[7] * g + s_m[8] * bl + s_bt[2];
    float guide = s_pb;
#pragma unroll
    for (int k = 0; k < 16; ++k) {
        guide += fmaxf(g0 - s_rt[k * 3 + 0], 0.0f) * s_ra[k * 3 + 0];
        guide += fmaxf(g1 - s_rt[k * 3 + 1], 0.0f) * s_ra[k * 3 + 1];
        guide += fmaxf(g2 - s_rt[k * 3 + 2], 0.0f) * s_ra[k * 3 + 2];
    }

    // grid coordinates (GD=8, GH=16, GW=16)
    float gx = (x + 0.5f) * (16.0f / WR);
    float gy = (y + 0.5f) * (16.0f / HR);
    float gz = fminf(fmaxf(guide, 0.0f), 1.0f) * 8.0f;
    float fxf = fmaxf(floorf(gx - 0.5f), 0.0f);
    float fyf = fmaxf(floorf(gy - 0.5f), 0.0f);
    float fzf = fmaxf(floorf(gz - 0.5f), 0.0f);
    float wx = gx - 0.5f - fxf;           // keeps sign (torch semantics)
    float wy = gy - 0.5f - fyf;           // keeps sign
    float wz = fabsf(gz - 0.5f - fzf);    // abs (torch semantics)
    int fx = (int)fxf; int cx = min(fx + 1, 15);
    int fy = (int)fyf; int cy = min(fy + 1, 15);
    int fz = (int)fzf; int cz = min(fz + 1, 7);

    const float* gp2 = grid + (size_t)b * 12 * 2048;
    int l_fff = fz * 256 + fy * 16 + fx;
    int l_cff = cz * 256 + fy * 16 + fx;
    int l_fcf = fz * 256 + cy * 16 + fx;
    int l_ccf = cz * 256 + cy * 16 + fx;
    int l_ffc = fz * 256 + fy * 16 + cx;
    int l_cfc = cz * 256 + fy * 16 + cx;
    int l_fcc = fz * 256 + cy * 16 + cx;
    int l_ccc = cz * 256 + cy * 16 + cx;

    float ex = 1.0f - wx, ey = 1.0f - wy, ez = 1.0f - wz;
    float w_fff = ex * ey * ez;
    float w_cff = ex * ey * wz;
    float w_fcf = ex * wy * ez;
    float w_ccf = ex * wy * wz;
    float w_ffc = wx * ey * ez;
    float w_cfc = wx * ey * wz;
    float w_fcc = wx * wy * ez;
    float w_ccc = wx * wy * wz;

    float a[12];
#pragma unroll
    for (int ch = 0; ch < 12; ++ch) {
        const float* gc = gp2 + ch * 2048;
        a[ch] = gc[l_fff] * w_fff + gc[l_cff] * w_cff
              + gc[l_fcf] * w_fcf + gc[l_ccf] * w_ccf
              + gc[l_ffc] * w_ffc + gc[l_cfc] * w_cfc
              + gc[l_fcc] * w_fcc + gc[l_ccc] * w_ccc;
    }

    size_t ob = (size_t)b * 3 * plane + (size_t)y * WR + x;
    out[ob]             = a[0] * r + a[1]  * g + a[2]  * bl + a[3];
    out[ob + plane]     = a[4] * r + a[5]  * g + a[6]  * bl + a[7];
    out[ob + 2 * plane] = a[8] * r + a[9]  * g + a[10] * bl + a[11];
}

extern "C" void kernel_launch(void* const* d_in, const int* in_sizes, int n_in,
                              void* d_out, int out_size, void* d_ws, size_t ws_size,
                              hipStream_t stream) {
    const float* high_res   = (const float*)d_in[0];
    const float* low_res    = (const float*)d_in[1];
    const float* ll1_w = (const float*)d_in[2];  const float* ll1_b = (const float*)d_in[3];
    const float* ll2_w = (const float*)d_in[4];  const float* ll2_b = (const float*)d_in[5];
    const float* ll3_w = (const float*)d_in[6];  const float* ll3_b = (const float*)d_in[7];
    const float* ll4_w = (const float*)d_in[8];  const float* ll4_b = (const float*)d_in[9];
    const float* lf1_w = (const float*)d_in[10]; const float* lf1_b = (const float*)d_in[11];
    const float* lf2_w = (const float*)d_in[12];
    const float* gf1_w = (const float*)d_in[13]; const float* gf1_b = (const float*)d_in[14];
    const float* gf2_w = (const float*)d_in[15]; const float* gf2_b = (const float*)d_in[16];
    const float* fc1_w = (const float*)d_in[17]; const float* fc1_b = (const float*)d_in[18];
    const float* fc2_w = (const float*)d_in[19]; const float* fc2_b = (const float*)d_in[20];
    const float* fc3_w = (const float*)d_in[21]; const float* fc3_b = (const float*)d_in[22];
    const float* pred_w = (const float*)d_in[23]; const float* pred_b = (const float*)d_in[24];
    const float* pw_mat = (const float*)d_in[25];
    const float* pw_bias = (const float*)d_in[26];
    const float* pw_bias_tag = (const float*)d_in[27];
    const float* rho_a = (const float*)d_in[28];
    const float* rho_t = (const float*)d_in[29];

    float* ws = (float*)d_ws;
    // workspace layout (floats)
    float* b1   = ws;                 // (2,8,128,128)  262144
    float* b2   = b1 + 262144;        // (2,16,64,64)   131072
    float* b3   = b2 + 131072;        // (2,32,32,32)    65536
    float* b4   = b3 + 65536;         // (2,64,16,16)    32768
    float* lf1o = b4 + 32768;         // (2,64,16,16)    32768
    float* lf2o = lf1o + 32768;       // (2,64,16,16)    32768
    float* gf1o = lf2o + 32768;       // (2,64,8,8)       8192
    float* gf2o = gf1o + 8192;        // (2,64,4,4)       2048
    float* fc1o = gf2o + 2048;        // (2,256)           512
    float* fc2o = fc1o + 512;         // (2,128)           256
    float* fc3o = fc2o + 256;         // (2,64)            128
    float* grid = fc3o + 128;         // (2,96,16,16)    49152

    float* out = (float*)d_out;
    dim3 blk(256);

    // low-res CNN
    conv3x3_kernel<<<cdiv(BS*8*128*128, 256),  blk, 0, stream>>>(low_res, ll1_w, ll1_b, b1, 3, 8, 256, 256, 128, 128, 2, 1);
    conv3x3_kernel<<<cdiv(BS*16*64*64, 256),   blk, 0, stream>>>(b1, ll2_w, ll2_b, b2, 8, 16, 128, 128, 64, 64, 2, 1);
    conv3x3_kernel<<<cdiv(BS*32*32*32, 256),   blk, 0, stream>>>(b2, ll3_w, ll3_b, b3, 16, 32, 64, 64, 32, 32, 2, 1);
    conv3x3_kernel<<<cdiv(BS*64*16*16, 256),   blk, 0, stream>>>(b3, ll4_w, ll4_b, b4, 32, 64, 32, 32, 16, 16, 2, 1);
    // local features
    conv3x3_kernel<<<cdiv(BS*64*16*16, 256),   blk, 0, stream>>>(b4, lf1_w, lf1_b, lf1o, 64, 64, 16, 16, 16, 16, 1, 1);
    conv3x3_kernel<<<cdiv(BS*64*16*16, 256),   blk, 0, stream>>>(lf1o, lf2_w, nullptr, lf2o, 64, 64, 16, 16, 16, 16, 1, 0);
    // global features
    conv3x3_kernel<<<cdiv(BS*64*8*8, 256),     blk, 0, stream>>>(b4, gf1_w, gf1_b, gf1o, 64, 64, 16, 16, 8, 8, 2, 1);
    conv3x3_kernel<<<cdiv(BS*64*4*4, 256),     blk, 0, stream>>>(gf1o, gf2_w, gf2_b, gf2o, 64, 64, 8, 8, 4, 4, 2, 1);
    // FC stack — one wave per output neuron
    fc_wave_kernel<<<cdiv(BS*256*64, 256), blk, 0, stream>>>(gf2o, fc1_w, fc1_b, fc1o, 1024, 256, 1);
    fc_wave_kernel<<<cdiv(BS*128*64, 256), blk, 0, stream>>>(fc1o, fc2_w, fc2_b, fc2o, 256, 128, 1);
    fc_wave_kernel<<<cdiv(BS*64*64, 256),  blk, 0, stream>>>(fc2o, fc3_w, fc3_b, fc3o, 128, 64, 0);
    // fusion + pred (bilateral grid)
    fuse_pred_kernel<<<cdiv(BS*96*256, 256), blk, 0, stream>>>(lf2o, fc3o, pred_w, pred_b, grid);
    // per-pixel guide + slice + assemble
    slice_kernel<<<cdiv(BS*HR*WR, 256), blk, 0, stream>>>(high_res, grid, pw_mat, pw_bias, pw_bias_tag,
                                                          rho_a, rho_t, out);
}

// Round 3
// 237.901 us; speedup vs baseline: 2.3829x; 1.6557x over previous
//
#include <hip/hip_runtime.h>

#define BS 2
#define HR 1024
#define WR 1024

static inline int cdiv(int a, int b) { return (a + b - 1) / b; }

// Thread-per-output 3x3 conv (for tiny Cin, e.g. first layer). NCHW / OIHW, pad=1.
__global__ void conv3x3_kernel(const float* __restrict__ in, const float* __restrict__ w,
                               const float* __restrict__ bias, float* __restrict__ out,
                               int Cin, int Cout, int Hin, int Win, int Hout, int Wout,
                               int stride, int do_relu) {
    int idx = blockIdx.x * blockDim.x + threadIdx.x;
    int total = BS * Cout * Hout * Wout;
    if (idx >= total) return;
    int ox = idx % Wout;
    int oy = (idx / Wout) % Hout;
    int oc = (idx / (Wout * Hout)) % Cout;
    int b  = idx / (Wout * Hout * Cout);

    float acc = bias ? bias[oc] : 0.0f;
    const float* wp = w + (size_t)oc * Cin * 9;
    const float* ip = in + (size_t)b * Cin * Hin * Win;
    int iy0 = oy * stride - 1;
    int ix0 = ox * stride - 1;
    for (int ic = 0; ic < Cin; ++ic) {
        const float* ipc = ip + (size_t)ic * Hin * Win;
        const float* wpc = wp + ic * 9;
#pragma unroll
        for (int ky = 0; ky < 3; ++ky) {
            int iy = iy0 + ky;
            if (iy < 0 || iy >= Hin) continue;
#pragma unroll
            for (int kx = 0; kx < 3; ++kx) {
                int ix = ix0 + kx;
                if (ix < 0 || ix >= Win) continue;
                acc += wpc[ky * 3 + kx] * ipc[iy * Win + ix];
            }
        }
    }
    if (do_relu) acc = fmaxf(acc, 0.0f);
    out[idx] = acc;
}

// Lane-group 3x3 conv: G lanes cooperate on one output, split over input channels,
// reduced with shfl_xor. G power of 2, groups aligned within a 64-lane wave.
template <int G>
__global__ void conv3x3_grp_kernel(const float* __restrict__ in, const float* __restrict__ w,
                                   const float* __restrict__ bias, float* __restrict__ out,
                                   int Cin, int Cout, int Hin, int Win, int Hout, int Wout,
                                   int stride, int do_relu) {
    int gid  = (blockIdx.x * blockDim.x + threadIdx.x) / G;
    int lane = threadIdx.x & (G - 1);
    int total = BS * Cout * Hout * Wout;
    if (gid >= total) return;
    int ox = gid % Wout;
    int oy = (gid / Wout) % Hout;
    int oc = (gid / (Wout * Hout)) % Cout;
    int b  = gid / (Wout * Hout * Cout);

    const float* wp = w + (size_t)oc * Cin * 9;
    const float* ip = in + (size_t)b * Cin * Hin * Win;
    int iy0 = oy * stride - 1;
    int ix0 = ox * stride - 1;

    float acc = 0.0f;
    for (int ic = lane; ic < Cin; ic += G) {
        const float* ipc = ip + (size_t)ic * Hin * Win;
        const float* wpc = wp + ic * 9;
#pragma unroll
        for (int ky = 0; ky < 3; ++ky) {
            int iy = iy0 + ky;
            if (iy < 0 || iy >= Hin) continue;
#pragma unroll
            for (int kx = 0; kx < 3; ++kx) {
                int ix = ix0 + kx;
                if (ix < 0 || ix >= Win) continue;
                acc += wpc[ky * 3 + kx] * ipc[iy * Win + ix];
            }
        }
    }
#pragma unroll
    for (int off = G >> 1; off > 0; off >>= 1) acc += __shfl_xor(acc, off, 64);
    if (lane == 0) {
        if (bias) acc += bias[oc];
        if (do_relu) acc = fmaxf(acc, 0.0f);
        out[gid] = acc;
    }
}

// Fully-connected, one 64-lane wave per output neuron.
__global__ void fc_wave_kernel(const float* __restrict__ in, const float* __restrict__ w,
                               const float* __restrict__ bias, float* __restrict__ out,
                               int In, int Out, int do_relu) {
    int wid  = (blockIdx.x * blockDim.x + threadIdx.x) >> 6;
    int lane = threadIdx.x & 63;
    if (wid >= BS * Out) return;
    int o = wid % Out;
    int b = wid / Out;
    const float* ip = in + (size_t)b * In;
    const float* wp = w + (size_t)o * In;

    float acc = 0.0f;
    for (int i = lane * 4; i < In; i += 64 * 4) {
        float4 wv = *reinterpret_cast<const float4*>(wp + i);
        float4 iv = *reinterpret_cast<const float4*>(ip + i);
        acc += wv.x * iv.x + wv.y * iv.y + wv.z * iv.z + wv.w * iv.w;
    }
#pragma unroll
    for (int off = 32; off > 0; off >>= 1) acc += __shfl_xor(acc, off, 64);
    if (lane == 0) {
        acc += bias[o];
        if (do_relu) acc = fmaxf(acc, 0.0f);
        out[(size_t)b * Out + o] = acc;
    }
}

// fusion = relu(gf[b,ic] + lf[b,ic,y,x]); grid = 1x1 conv(pred_w,pred_b) -> (BS,96,16,16)
__global__ void fuse_pred_kernel(const float* __restrict__ lf, const float* __restrict__ gfv,
                                 const float* __restrict__ pw, const float* __restrict__ pb,
                                 float* __restrict__ grid) {
    int gid  = (blockIdx.x * blockDim.x + threadIdx.x) >> 4;  // 16 lanes per output
    int lane = threadIdx.x & 15;
    int total = BS * 96 * 256;
    if (gid >= total) return;
    int sp = gid % 256;
    int oc = (gid / 256) % 96;
    int b  = gid / (256 * 96);
    const float* lfp = lf + (size_t)b * 64 * 256;
    const float* gp  = gfv + (size_t)b * 64;
    const float* wp  = pw + oc * 64;
    float acc = 0.0f;
#pragma unroll
    for (int ic = lane; ic < 64; ic += 16) {
        float f = fmaxf(gp[ic] + lfp[ic * 256 + sp], 0.0f);
        acc += wp[ic] * f;
    }
#pragma unroll
    for (int off = 8; off > 0; off >>= 1) acc += __shfl_xor(acc, off, 64);
    if (lane == 0) grid[gid] = acc + pb[oc];
}

// Per-pixel: guide curve + trilinear bilateral-grid slice + affine assembly.
__global__ void slice_kernel(const float* __restrict__ hr, const float* __restrict__ grid,
                             const float* __restrict__ pw_mat, const float* __restrict__ pw_bias,
                             const float* __restrict__ pw_bias_tag,
                             const float* __restrict__ rho_a, const float* __restrict__ rho_t,
                             float* __restrict__ out) {
    __shared__ float s_rt[48], s_ra[48], s_m[9], s_bt[3], s_pb;
    int t = threadIdx.x;
    if (t < 48) { s_rt[t] = rho_t[t]; s_ra[t] = rho_a[t]; }
    if (t < 9)  s_m[t] = pw_mat[t];
    if (t < 3)  s_bt[t] = pw_bias_tag[t];
    if (t == 0) s_pb = pw_bias[0];
    __syncthreads();

    int idx = blockIdx.x * blockDim.x + t;
    int total = BS * HR * WR;
    if (idx >= total) return;
    int x = idx % WR;
    int y = (idx / WR) % HR;
    int b = idx / (WR * HR);

    const size_t plane = (size_t)HR * WR;
    const float* hp = hr + (size_t)b * 3 * plane + (size_t)y * WR + x;
    float r  = hp[0];
    float g  = hp[plane];
    float bl = hp[2 * plane];

    // guide
    float g0 = s_m[0] * r + s_m[1] * g + s_m[2] * bl + s_bt[0];
    float g1 = s_m[3] * r + s_m[4] * g + s_m[5] * bl + s_bt[1];
    float g2 = s_m[6] * r + s_m[7] * g + s_m[8] * bl + s_bt[2];
    float guide = s_pb;
#pragma unroll
    for (int k = 0; k < 16; ++k) {
        guide += fmaxf(g0 - s_rt[k * 3 + 0], 0.0f) * s_ra[k * 3 + 0];
        guide += fmaxf(g1 - s_rt[k * 3 + 1], 0.0f) * s_ra[k * 3 + 1];
        guide += fmaxf(g2 - s_rt[k * 3 + 2], 0.0f) * s_ra[k * 3 + 2];
    }

    // grid coordinates (GD=8, GH=16, GW=16)
    float gx = (x + 0.5f) * (16.0f / WR);
    float gy = (y + 0.5f) * (16.0f / HR);
    float gz = fminf(fmaxf(guide, 0.0f), 1.0f) * 8.0f;
    float fxf = fmaxf(floorf(gx - 0.5f), 0.0f);
    float fyf = fmaxf(floorf(gy - 0.5f), 0.0f);
    float fzf = fmaxf(floorf(gz - 0.5f), 0.0f);
    float wx = gx - 0.5f - fxf;           // keeps sign (torch semantics)
    float wy = gy - 0.5f - fyf;           // keeps sign
    float wz = fabsf(gz - 0.5f - fzf);    // abs (torch semantics)
    int fx = (int)fxf; int cx = min(fx + 1, 15);
    int fy = (int)fyf; int cy = min(fy + 1, 15);
    int fz = (int)fzf; int cz = min(fz + 1, 7);

    const float* gp2 = grid + (size_t)b * 12 * 2048;
    int l_fff = fz * 256 + fy * 16 + fx;
    int l_cff = cz * 256 + fy * 16 + fx;
    int l_fcf = fz * 256 + cy * 16 + fx;
    int l_ccf = cz * 256 + cy * 16 + fx;
    int l_ffc = fz * 256 + fy * 16 + cx;
    int l_cfc = cz * 256 + fy * 16 + cx;
    int l_fcc = fz * 256 + cy * 16 + cx;
    int l_ccc = cz * 256 + cy * 16 + cx;

    float ex = 1.0f - wx, ey = 1.0f - wy, ez = 1.0f - wz;
    float w_fff = ex * ey * ez;
    float w_cff = ex * ey * wz;
    float w_fcf = ex * wy * ez;
    float w_ccf = ex * wy * wz;
    float w_ffc = wx * ey * ez;
    float w_cfc = wx * ey * wz;
    float w_fcc = wx * wy * ez;
    float w_ccc = wx * wy * wz;

    float a[12];
#pragma unroll
    for (int ch = 0; ch < 12; ++ch) {
        const float* gc = gp2 + ch * 2048;
        a[ch] = gc[l_fff] * w_fff + gc[l_cff] * w_cff
              + gc[l_fcf] * w_fcf + gc[l_ccf] * w_ccf
              + gc[l_ffc] * w_ffc + gc[l_cfc] * w_cfc
              + gc[l_fcc] * w_fcc + gc[l_ccc] * w_ccc;
    }

    size_t ob = (size_t)b * 3 * plane + (size_t)y * WR + x;
    out[ob]             = a[0] * r + a[1]  * g + a[2]  * bl + a[3];
    out[ob + plane]     = a[4] * r + a[5]  * g + a[6]  * bl + a[7];
    out[ob + 2 * plane] = a[8] * r + a[9]  * g + a[10] * bl + a[11];
}

extern "C" void kernel_launch(void* const* d_in, const int* in_sizes, int n_in,
                              void* d_out, int out_size, void* d_ws, size_t ws_size,
                              hipStream_t stream) {
    const float* high_res   = (const float*)d_in[0];
    const float* low_res    = (const float*)d_in[1];
    const float* ll1_w = (const float*)d_in[2];  const float* ll1_b = (const float*)d_in[3];
    const float* ll2_w = (const float*)d_in[4];  const float* ll2_b = (const float*)d_in[5];
    const float* ll3_w = (const float*)d_in[6];  const float* ll3_b = (const float*)d_in[7];
    const float* ll4_w = (const float*)d_in[8];  const float* ll4_b = (const float*)d_in[9];
    const float* lf1_w = (const float*)d_in[10]; const float* lf1_b = (const float*)d_in[11];
    const float* lf2_w = (const float*)d_in[12];
    const float* gf1_w = (const float*)d_in[13]; const float* gf1_b = (const float*)d_in[14];
    const float* gf2_w = (const float*)d_in[15]; const float* gf2_b = (const float*)d_in[16];
    const float* fc1_w = (const float*)d_in[17]; const float* fc1_b = (const float*)d_in[18];
    const float* fc2_w = (const float*)d_in[19]; const float* fc2_b = (const float*)d_in[20];
    const float* fc3_w = (const float*)d_in[21]; const float* fc3_b = (const float*)d_in[22];
    const float* pred_w = (const float*)d_in[23]; const float* pred_b = (const float*)d_in[24];
    const float* pw_mat = (const float*)d_in[25];
    const float* pw_bias = (const float*)d_in[26];
    const float* pw_bias_tag = (const float*)d_in[27];
    const float* rho_a = (const float*)d_in[28];
    const float* rho_t = (const float*)d_in[29];

    float* ws = (float*)d_ws;
    float* b1   = ws;                 // (2,8,128,128)  262144
    float* b2   = b1 + 262144;        // (2,16,64,64)   131072
    float* b3   = b2 + 131072;        // (2,32,32,32)    65536
    float* b4   = b3 + 65536;         // (2,64,16,16)    32768
    float* lf1o = b4 + 32768;         // (2,64,16,16)    32768
    float* lf2o = lf1o + 32768;       // (2,64,16,16)    32768
    float* gf1o = lf2o + 32768;       // (2,64,8,8)       8192
    float* gf2o = gf1o + 8192;        // (2,64,4,4)       2048
    float* fc1o = gf2o + 2048;        // (2,256)           512
    float* fc2o = fc1o + 512;         // (2,128)           256
    float* fc3o = fc2o + 256;         // (2,64)            128
    float* grid = fc3o + 128;         // (2,96,16,16)    49152

    float* out = (float*)d_out;
    dim3 blk(256);

    // low-res CNN trunk — lane-group convs sized so every dispatch has >=2K waves
    conv3x3_kernel<<<cdiv(BS*8*128*128, 256), blk, 0, stream>>>(low_res, ll1_w, ll1_b, b1, 3, 8, 256, 256, 128, 128, 2, 1);
    conv3x3_grp_kernel<8><<<cdiv(BS*16*64*64*8, 256), blk, 0, stream>>>(b1, ll2_w, ll2_b, b2, 8, 16, 128, 128, 64, 64, 2, 1);
    conv3x3_grp_kernel<16><<<cdiv(BS*32*32*32*16, 256), blk, 0, stream>>>(b2, ll3_w, ll3_b, b3, 16, 32, 64, 64, 32, 32, 2, 1);
    conv3x3_grp_kernel<32><<<cdiv(BS*64*16*16*32, 256), blk, 0, stream>>>(b3, ll4_w, ll4_b, b4, 32, 64, 32, 32, 16, 16, 2, 1);
    // local features
    conv3x3_grp_kernel<64><<<cdiv(BS*64*16*16*64, 256), blk, 0, stream>>>(b4, lf1_w, lf1_b, lf1o, 64, 64, 16, 16, 16, 16, 1, 1);
    conv3x3_grp_kernel<64><<<cdiv(BS*64*16*16*64, 256), blk, 0, stream>>>(lf1o, lf2_w, nullptr, lf2o, 64, 64, 16, 16, 16, 16, 1, 0);
    // global features
    conv3x3_grp_kernel<64><<<cdiv(BS*64*8*8*64, 256), blk, 0, stream>>>(b4, gf1_w, gf1_b, gf1o, 64, 64, 16, 16, 8, 8, 2, 1);
    conv3x3_grp_kernel<64><<<cdiv(BS*64*4*4*64, 256), blk, 0, stream>>>(gf1o, gf2_w, gf2_b, gf2o, 64, 64, 8, 8, 4, 4, 2, 1);
    // FC stack — one wave per output neuron
    fc_wave_kernel<<<cdiv(BS*256*64, 256), blk, 0, stream>>>(gf2o, fc1_w, fc1_b, fc1o, 1024, 256, 1);
    fc_wave_kernel<<<cdiv(BS*128*64, 256), blk, 0, stream>>>(fc1o, fc2_w, fc2_b, fc2o, 256, 128, 1);
    fc_wave_kernel<<<cdiv(BS*64*64, 256),  blk, 0, stream>>>(fc2o, fc3_w, fc3_b, fc3o, 128, 64, 0);
    // fusion + pred (bilateral grid)
    fuse_pred_kernel<<<cdiv(BS*96*256*16, 256), blk, 0, stream>>>(lf2o, fc3o, pred_w, pred_b, grid);
    // per-pixel guide + slice + assemble
    slice_kernel<<<cdiv(BS*HR*WR, 256), blk, 0, stream>>>(high_res, grid, pw_mat, pw_bias, pw_bias_tag,
                                                          rho_a, rho_t, out);
}

// Round 4
// 223.959 us; speedup vs baseline: 2.5313x; 1.0623x over previous
//
#include <hip/hip_runtime.h>

#define BS 2
#define HR 1024
#define WR 1024

static inline int cdiv(int a, int b) { return (a + b - 1) / b; }

// Thread-per-output 3x3 conv (for tiny Cin, e.g. first layer). NCHW / OIHW, pad=1.
__global__ void conv3x3_kernel(const float* __restrict__ in, const float* __restrict__ w,
                               const float* __restrict__ bias, float* __restrict__ out,
                               int Cin, int Cout, int Hin, int Win, int Hout, int Wout,
                               int stride, int do_relu) {
    int idx = blockIdx.x * blockDim.x + threadIdx.x;
    int total = BS * Cout * Hout * Wout;
    if (idx >= total) return;
    int ox = idx % Wout;
    int oy = (idx / Wout) % Hout;
    int oc = (idx / (Wout * Hout)) % Cout;
    int b  = idx / (Wout * Hout * Cout);

    float acc = bias ? bias[oc] : 0.0f;
    const float* wp = w + (size_t)oc * Cin * 9;
    const float* ip = in + (size_t)b * Cin * Hin * Win;
    int iy0 = oy * stride - 1;
    int ix0 = ox * stride - 1;
    for (int ic = 0; ic < Cin; ++ic) {
        const float* ipc = ip + (size_t)ic * Hin * Win;
        const float* wpc = wp + ic * 9;
#pragma unroll
        for (int ky = 0; ky < 3; ++ky) {
            int iy = iy0 + ky;
            if (iy < 0 || iy >= Hin) continue;
#pragma unroll
            for (int kx = 0; kx < 3; ++kx) {
                int ix = ix0 + kx;
                if (ix < 0 || ix >= Win) continue;
                acc += wpc[ky * 3 + kx] * ipc[iy * Win + ix];
            }
        }
    }
    if (do_relu) acc = fmaxf(acc, 0.0f);
    out[idx] = acc;
}

// Lane-group 3x3 conv: G lanes cooperate on one output, split over input channels.
template <int G>
__global__ void conv3x3_grp_kernel(const float* __restrict__ in, const float* __restrict__ w,
                                   const float* __restrict__ bias, float* __restrict__ out,
                                   int Cin, int Cout, int Hin, int Win, int Hout, int Wout,
                                   int stride, int do_relu) {
    int gid  = (blockIdx.x * blockDim.x + threadIdx.x) / G;
    int lane = threadIdx.x & (G - 1);
    int total = BS * Cout * Hout * Wout;
    if (gid >= total) return;
    int ox = gid % Wout;
    int oy = (gid / Wout) % Hout;
    int oc = (gid / (Wout * Hout)) % Cout;
    int b  = gid / (Wout * Hout * Cout);

    const float* wp = w + (size_t)oc * Cin * 9;
    const float* ip = in + (size_t)b * Cin * Hin * Win;
    int iy0 = oy * stride - 1;
    int ix0 = ox * stride - 1;

    float acc = 0.0f;
    for (int ic = lane; ic < Cin; ic += G) {
        const float* ipc = ip + (size_t)ic * Hin * Win;
        const float* wpc = wp + ic * 9;
#pragma unroll
        for (int ky = 0; ky < 3; ++ky) {
            int iy = iy0 + ky;
            if (iy < 0 || iy >= Hin) continue;
#pragma unroll
            for (int kx = 0; kx < 3; ++kx) {
                int ix = ix0 + kx;
                if (ix < 0 || ix >= Win) continue;
                acc += wpc[ky * 3 + kx] * ipc[iy * Win + ix];
            }
        }
    }
#pragma unroll
    for (int off = G >> 1; off > 0; off >>= 1) acc += __shfl_xor(acc, off, 64);
    if (lane == 0) {
        if (bias) acc += bias[oc];
        if (do_relu) acc = fmaxf(acc, 0.0f);
        out[gid] = acc;
    }
}

// Fully-connected, one 64-lane wave per output neuron.
__global__ void fc_wave_kernel(const float* __restrict__ in, const float* __restrict__ w,
                               const float* __restrict__ bias, float* __restrict__ out,
                               int In, int Out, int do_relu) {
    int wid  = (blockIdx.x * blockDim.x + threadIdx.x) >> 6;
    int lane = threadIdx.x & 63;
    if (wid >= BS * Out) return;
    int o = wid % Out;
    int b = wid / Out;
    const float* ip = in + (size_t)b * In;
    const float* wp = w + (size_t)o * In;

    float acc = 0.0f;
    for (int i = lane * 4; i < In; i += 64 * 4) {
        float4 wv = *reinterpret_cast<const float4*>(wp + i);
        float4 iv = *reinterpret_cast<const float4*>(ip + i);
        acc += wv.x * iv.x + wv.y * iv.y + wv.z * iv.z + wv.w * iv.w;
    }
#pragma unroll
    for (int off = 32; off > 0; off >>= 1) acc += __shfl_xor(acc, off, 64);
    if (lane == 0) {
        acc += bias[o];
        if (do_relu) acc = fmaxf(acc, 0.0f);
        out[(size_t)b * Out + o] = acc;
    }
}

// fusion = relu(gf + lf); 1x1 conv -> CHANNEL-INTERLEAVED grid gt[b][z][y][x][12]
__global__ void fuse_pred_kernel(const float* __restrict__ lf, const float* __restrict__ gfv,
                                 const float* __restrict__ pw, const float* __restrict__ pb,
                                 float* __restrict__ gt) {
    int gid  = (blockIdx.x * blockDim.x + threadIdx.x) >> 4;  // 16 lanes per output
    int lane = threadIdx.x & 15;
    int total = BS * 96 * 256;
    if (gid >= total) return;
    int sp = gid % 256;
    int oc = (gid / 256) % 96;
    int b  = gid / (256 * 96);
    const float* lfp = lf + (size_t)b * 64 * 256;
    const float* gp  = gfv + (size_t)b * 64;
    const float* wp  = pw + oc * 64;
    float acc = 0.0f;
#pragma unroll
    for (int ic = lane; ic < 64; ic += 16) {
        float f = fmaxf(gp[ic] + lfp[ic * 256 + sp], 0.0f);
        acc += wp[ic] * f;
    }
#pragma unroll
    for (int off = 8; off > 0; off >>= 1) acc += __shfl_xor(acc, off, 64);
    if (lane == 0) {
        int z = oc & 7, c12 = oc >> 3;          // pred ch = c12*8 + z
        int y = sp >> 4, x = sp & 15;
        gt[((size_t)b * 2048 + (size_t)(z * 16 + y) * 16 + x) * 12 + c12] = acc + pb[oc];
    }
}

// Per-pixel: guide curve + trilinear slice (channel-interleaved grid) + affine.
// 4 pixels per thread, float4 I/O.
__global__ void slice4_kernel(const float* __restrict__ hr, const float* __restrict__ gt,
                              const float* __restrict__ pw_mat, const float* __restrict__ pw_bias,
                              const float* __restrict__ pw_bias_tag,
                              const float* __restrict__ rho_a, const float* __restrict__ rho_t,
                              float* __restrict__ out) {
    __shared__ float s_rt[48], s_ra[48], s_m[9], s_bt[3], s_pb;
    int t = threadIdx.x;
    if (t < 48) { s_rt[t] = rho_t[t]; s_ra[t] = rho_a[t]; }
    if (t < 9)  s_m[t] = pw_mat[t];
    if (t < 3)  s_bt[t] = pw_bias_tag[t];
    if (t == 0) s_pb = pw_bias[0];
    __syncthreads();

    const int NXQ = WR / 4;
    int idx = blockIdx.x * blockDim.x + t;
    if (idx >= BS * HR * NXQ) return;
    int xq = idx % NXQ;
    int y  = (idx / NXQ) % HR;
    int b  = idx / (NXQ * HR);
    int x0 = xq * 4;

    const size_t plane = (size_t)HR * WR;
    const float* hp = hr + (size_t)b * 3 * plane + (size_t)y * WR + x0;
    float4 R4 = *reinterpret_cast<const float4*>(hp);
    float4 G4 = *reinterpret_cast<const float4*>(hp + plane);
    float4 B4 = *reinterpret_cast<const float4*>(hp + 2 * plane);
    float rr[4] = {R4.x, R4.y, R4.z, R4.w};
    float gg[4] = {G4.x, G4.y, G4.z, G4.w};
    float bb[4] = {B4.x, B4.y, B4.z, B4.w};

    // y-dependent terms (shared by all 4 pixels)
    float gyv = (y + 0.5f) * (16.0f / HR);
    float fyf = fmaxf(floorf(gyv - 0.5f), 0.0f);
    float wyv = gyv - 0.5f - fyf;                 // keeps sign
    int fy = (int)fyf; int cy = min(fy + 1, 15);
    float ey = 1.0f - wyv;

    const float* gbase = gt + (size_t)b * 24576;  // 2048 * 12
    float o0[4], o1[4], o2[4];

#pragma unroll
    for (int j = 0; j < 4; ++j) {
        int x = x0 + j;
        float r = rr[j], g = gg[j], bl = bb[j];

        // guide
        float g0 = s_m[0] * r + s_m[1] * g + s_m[2] * bl + s_bt[0];
        float g1 = s_m[3] * r + s_m[4] * g + s_m[5] * bl + s_bt[1];
        float g2 = s_m[6] * r + s_m[7] * g + s_m[8] * bl + s_bt[2];
        float guide = s_pb;
#pragma unroll
        for (int k = 0; k < 16; ++k) {
            guide += fmaxf(g0 - s_rt[k * 3 + 0], 0.0f) * s_ra[k * 3 + 0];
            guide += fmaxf(g1 - s_rt[k * 3 + 1], 0.0f) * s_ra[k * 3 + 1];
            guide += fmaxf(g2 - s_rt[k * 3 + 2], 0.0f) * s_ra[k * 3 + 2];
        }

        float gx = (x + 0.5f) * (16.0f / WR);
        float gz = fminf(fmaxf(guide, 0.0f), 1.0f) * 8.0f;
        float fxf = fmaxf(floorf(gx - 0.5f), 0.0f);
        float fzf = fmaxf(floorf(gz - 0.5f), 0.0f);
        float wxv = gx - 0.5f - fxf;              // keeps sign
        float wzv = fabsf(gz - 0.5f - fzf);       // abs
        int fx = (int)fxf; int cx = min(fx + 1, 15);
        int fz = (int)fzf; int cz = min(fz + 1, 7);
        float ex = 1.0f - wxv, ez = 1.0f - wzv;

        // corner base offsets (channel-interleaved: ((z*16+y)*16+x)*12)
        int o_ff = (fz * 256 + fy * 16 + fx) * 12;
        int o_cf = (cz * 256 + fy * 16 + fx) * 12;
        int o_fc = (fz * 256 + cy * 16 + fx) * 12;
        int o_cc = (cz * 256 + cy * 16 + fx) * 12;
        int dxo  = (cx - fx) * 12;

        float w_fff = ex * ey * ez, w_cff = ex * ey * wzv;
        float w_fcf = ex * wyv * ez, w_ccf = ex * wyv * wzv;
        float w_ffc = wxv * ey * ez, w_cfc = wxv * ey * wzv;
        float w_fcc = wxv * wyv * ez, w_ccc = wxv * wyv * wzv;

        float4 a0 = {0,0,0,0}, a1 = {0,0,0,0}, a2 = {0,0,0,0};
        const int offs[8] = {o_ff, o_cf, o_fc, o_cc, o_ff + dxo, o_cf + dxo, o_fc + dxo, o_cc + dxo};
        const float wts[8] = {w_fff, w_cff, w_fcf, w_ccf, w_ffc, w_cfc, w_fcc, w_ccc};
#pragma unroll
        for (int c = 0; c < 8; ++c) {
            const float* p = gbase + offs[c];
            float4 v0 = *reinterpret_cast<const float4*>(p);
            float4 v1 = *reinterpret_cast<const float4*>(p + 4);
            float4 v2 = *reinterpret_cast<const float4*>(p + 8);
            float wv = wts[c];
            a0.x += wv * v0.x; a0.y += wv * v0.y; a0.z += wv * v0.z; a0.w += wv * v0.w;
            a1.x += wv * v1.x; a1.y += wv * v1.y; a1.z += wv * v1.z; a1.w += wv * v1.w;
            a2.x += wv * v2.x; a2.y += wv * v2.y; a2.z += wv * v2.z; a2.w += wv * v2.w;
        }
        o0[j] = a0.x * r + a0.y * g + a0.z * bl + a0.w;
        o1[j] = a1.x * r + a1.y * g + a1.z * bl + a1.w;
        o2[j] = a2.x * r + a2.y * g + a2.z * bl + a2.w;
    }

    float* op = out + (size_t)b * 3 * plane + (size_t)y * WR + x0;
    *reinterpret_cast<float4*>(op)              = make_float4(o0[0], o0[1], o0[2], o0[3]);
    *reinterpret_cast<float4*>(op + plane)      = make_float4(o1[0], o1[1], o1[2], o1[3]);
    *reinterpret_cast<float4*>(op + 2 * plane)  = make_float4(o2[0], o2[1], o2[2], o2[3]);
}

extern "C" void kernel_launch(void* const* d_in, const int* in_sizes, int n_in,
                              void* d_out, int out_size, void* d_ws, size_t ws_size,
                              hipStream_t stream) {
    const float* high_res   = (const float*)d_in[0];
    const float* low_res    = (const float*)d_in[1];
    const float* ll1_w = (const float*)d_in[2];  const float* ll1_b = (const float*)d_in[3];
    const float* ll2_w = (const float*)d_in[4];  const float* ll2_b = (const float*)d_in[5];
    const float* ll3_w = (const float*)d_in[6];  const float* ll3_b = (const float*)d_in[7];
    const float* ll4_w = (const float*)d_in[8];  const float* ll4_b = (const float*)d_in[9];
    const float* lf1_w = (const float*)d_in[10]; const float* lf1_b = (const float*)d_in[11];
    const float* lf2_w = (const float*)d_in[12];
    const float* gf1_w = (const float*)d_in[13]; const float* gf1_b = (const float*)d_in[14];
    const float* gf2_w = (const float*)d_in[15]; const float* gf2_b = (const float*)d_in[16];
    const float* fc1_w = (const float*)d_in[17]; const float* fc1_b = (const float*)d_in[18];
    const float* fc2_w = (const float*)d_in[19]; const float* fc2_b = (const float*)d_in[20];
    const float* fc3_w = (const float*)d_in[21]; const float* fc3_b = (const float*)d_in[22];
    const float* pred_w = (const float*)d_in[23]; const float* pred_b = (const float*)d_in[24];
    const float* pw_mat = (const float*)d_in[25];
    const float* pw_bias = (const float*)d_in[26];
    const float* pw_bias_tag = (const float*)d_in[27];
    const float* rho_a = (const float*)d_in[28];
    const float* rho_t = (const float*)d_in[29];

    float* ws = (float*)d_ws;
    float* b1   = ws;                 // (2,8,128,128)  262144
    float* b2   = b1 + 262144;        // (2,16,64,64)   131072
    float* b3   = b2 + 131072;        // (2,32,32,32)    65536
    float* b4   = b3 + 65536;         // (2,64,16,16)    32768
    float* lf1o = b4 + 32768;         // (2,64,16,16)    32768
    float* lf2o = lf1o + 32768;       // (2,64,16,16)    32768
    float* gf1o = lf2o + 32768;       // (2,64,8,8)       8192
    float* gf2o = gf1o + 8192;        // (2,64,4,4)       2048
    float* fc1o = gf2o + 2048;        // (2,256)           512
    float* fc2o = fc1o + 512;         // (2,128)           256
    float* fc3o = fc2o + 256;         // (2,64)            128
    float* gt   = fc3o + 128;         // (2,2048,12)     49152  channel-interleaved grid

    float* out = (float*)d_out;
    dim3 blk(256);

    // low-res CNN trunk
    conv3x3_kernel<<<cdiv(BS*8*128*128, 256), blk, 0, stream>>>(low_res, ll1_w, ll1_b, b1, 3, 8, 256, 256, 128, 128, 2, 1);
    conv3x3_grp_kernel<8><<<cdiv(BS*16*64*64*8, 256), blk, 0, stream>>>(b1, ll2_w, ll2_b, b2, 8, 16, 128, 128, 64, 64, 2, 1);
    conv3x3_grp_kernel<16><<<cdiv(BS*32*32*32*16, 256), blk, 0, stream>>>(b2, ll3_w, ll3_b, b3, 16, 32, 64, 64, 32, 32, 2, 1);
    conv3x3_grp_kernel<32><<<cdiv(BS*64*16*16*32, 256), blk, 0, stream>>>(b3, ll4_w, ll4_b, b4, 32, 64, 32, 32, 16, 16, 2, 1);
    // local features
    conv3x3_grp_kernel<64><<<cdiv(BS*64*16*16*64, 256), blk, 0, stream>>>(b4, lf1_w, lf1_b, lf1o, 64, 64, 16, 16, 16, 16, 1, 1);
    conv3x3_grp_kernel<64><<<cdiv(BS*64*16*16*64, 256), blk, 0, stream>>>(lf1o, lf2_w, nullptr, lf2o, 64, 64, 16, 16, 16, 16, 1, 0);
    // global features
    conv3x3_grp_kernel<64><<<cdiv(BS*64*8*8*64, 256), blk, 0, stream>>>(b4, gf1_w, gf1_b, gf1o, 64, 64, 16, 16, 8, 8, 2, 1);
    conv3x3_grp_kernel<64><<<cdiv(BS*64*4*4*64, 256), blk, 0, stream>>>(gf1o, gf2_w, gf2_b, gf2o, 64, 64, 8, 8, 4, 4, 2, 1);
    // FC stack
    fc_wave_kernel<<<cdiv(BS*256*64, 256), blk, 0, stream>>>(gf2o, fc1_w, fc1_b, fc1o, 1024, 256, 1);
    fc_wave_kernel<<<cdiv(BS*128*64, 256), blk, 0, stream>>>(fc1o, fc2_w, fc2_b, fc2o, 256, 128, 1);
    fc_wave_kernel<<<cdiv(BS*64*64, 256),  blk, 0, stream>>>(fc2o, fc3_w, fc3_b, fc3o, 128, 64, 0);
    // fusion + pred -> channel-interleaved grid
    fuse_pred_kernel<<<cdiv(BS*96*256*16, 256), blk, 0, stream>>>(lf2o, fc3o, pred_w, pred_b, gt);
    // per-pixel guide + slice + assemble (4 px/thread)
    slice4_kernel<<<cdiv(BS*HR*WR/4, 256), blk, 0, stream>>>(high_res, gt, pw_mat, pw_bias, pw_bias_tag,
                                                             rho_a, rho_t, out);
}

// Round 5
// 130.087 us; speedup vs baseline: 4.3578x; 1.7216x over previous
//
#include <hip/hip_runtime.h>

#define BS 2
#define HR 1024
#define WR 1024

static inline int cdiv(int a, int b) { return (a + b - 1) / b; }

// ---------------------------------------------------------------------------
// Weight repack (runs every call, fully parallel, one launch):
//  - 7 conv layers:  w[oc][ic][ky][kx]  ->  wT[k][ic/4][oc][ic%4]
//  - fc1:            w[o][c*16+s]       ->  wT[o][s*64+c]   (NCHW->NHWC flatten)
__global__ void repack_kernel(const float* __restrict__ s0, const float* __restrict__ s1,
                              const float* __restrict__ s2, const float* __restrict__ s3,
                              const float* __restrict__ s4, const float* __restrict__ s5,
                              const float* __restrict__ s6,
                              float* __restrict__ d0, float* __restrict__ d1,
                              float* __restrict__ d2, float* __restrict__ d3,
                              float* __restrict__ d4, float* __restrict__ d5,
                              float* __restrict__ d6,
                              const float* __restrict__ fcs, float* __restrict__ fcd) {
    const int CONV_TOTAL = 171648;           // sum of cout*cin*9
    int idx = blockIdx.x * blockDim.x + threadIdx.x;
    if (idx < CONV_TOTAL) {
        const float* src[7] = {s0, s1, s2, s3, s4, s5, s6};
        float* dst[7]       = {d0, d1, d2, d3, d4, d5, d6};
        const int cout[7] = {16, 32, 64, 64, 64, 64, 64};
        const int cin[7]  = {8, 16, 32, 64, 64, 64, 64};
        const int sz[7]   = {1152, 4608, 18432, 36864, 36864, 36864, 36864};
        int l = 0, e = idx;
        while (e >= sz[l]) { e -= sz[l]; ++l; }
        int Cin = cin[l], Cout = cout[l];
        int oc = e / (Cin * 9);
        int rem = e - oc * Cin * 9;
        int ic = rem / 9;
        int k  = rem - ic * 9;
        dst[l][((k * (Cin >> 2) + (ic >> 2)) * Cout + oc) * 4 + (ic & 3)] = src[l][e];
    } else {
        int e = idx - CONV_TOTAL;            // fc1: 256*1024 = 262144 elements
        if (e >= 262144) return;
        int o = e >> 10, j = e & 1023;
        int s = j >> 6, c = j & 63;
        fcd[e] = fcs[(o << 10) + (c << 4) + s];
    }
}

// ---------------------------------------------------------------------------
// ll1: NCHW input (2,3,256,256), stride 2, pad 1 -> NHWC output (2,128,128,8).
// One thread per output pixel computes all 8 output channels.
__global__ void ll1_nhwc_kernel(const float* __restrict__ in, const float* __restrict__ w,
                                const float* __restrict__ bias, float* __restrict__ out) {
    int idx = blockIdx.x * blockDim.x + threadIdx.x;
    if (idx >= BS * 128 * 128) return;
    int ox = idx & 127;
    int oy = (idx >> 7) & 127;
    int b  = idx >> 14;

    float acc[8];
#pragma unroll
    for (int oc = 0; oc < 8; ++oc) acc[oc] = bias[oc];

#pragma unroll
    for (int ky = 0; ky < 3; ++ky) {
        int iy = 2 * oy - 1 + ky;
        if (iy < 0 || iy >= 256) continue;
#pragma unroll
        for (int kx = 0; kx < 3; ++kx) {
            int ix = 2 * ox - 1 + kx;
            if (ix < 0 || ix >= 256) continue;
#pragma unroll
            for (int ic = 0; ic < 3; ++ic) {
                float v = in[(((size_t)b * 3 + ic) * 256 + iy) * 256 + ix];
#pragma unroll
                for (int oc = 0; oc < 8; ++oc)
                    acc[oc] += w[oc * 27 + ic * 9 + ky * 3 + kx] * v;
            }
        }
    }
    float* op = out + (size_t)idx * 8;
#pragma unroll
    for (int oc = 0; oc < 8; ++oc) op[oc] = fmaxf(acc[oc], 0.0f);
}

// ---------------------------------------------------------------------------
// NHWC conv3x3, pad 1: lane = oc (coalesced float4 weight loads from repacked
// wT[k][ic/4][oc][4]); input float4 is uniform across the oc-lane group.
template <int COUT, int CIN, bool RELU, bool HASBIAS>
__global__ void conv_nhwc_kernel(const float* __restrict__ in, const float* __restrict__ wT,
                                 const float* __restrict__ bias, float* __restrict__ out,
                                 int Hin, int Win, int Hout, int Wout, int stride) {
    int idx = blockIdx.x * blockDim.x + threadIdx.x;
    int total = BS * Hout * Wout * COUT;
    if (idx >= total) return;
    int oc  = idx & (COUT - 1);
    int pix = idx / COUT;
    int ox = pix % Wout;
    int oy = (pix / Wout) % Hout;
    int b  = pix / (Wout * Hout);

    int iy0 = oy * stride - 1;
    int ix0 = ox * stride - 1;
    float acc = 0.0f;
#pragma unroll
    for (int ky = 0; ky < 3; ++ky) {
        int iy = iy0 + ky;
        if (iy < 0 || iy >= Hin) continue;
#pragma unroll
        for (int kx = 0; kx < 3; ++kx) {
            int ix = ix0 + kx;
            if (ix < 0 || ix >= Win) continue;
            int k = ky * 3 + kx;
            const float* wp = wT + ((size_t)k * (CIN / 4) * COUT + oc) * 4;
            const float* ip = in + ((size_t)(b * Hin + iy) * Win + ix) * CIN;
#pragma unroll
            for (int ic4 = 0; ic4 < CIN / 4; ++ic4) {
                float4 wv = *reinterpret_cast<const float4*>(wp + (size_t)ic4 * COUT * 4);
                float4 iv = *reinterpret_cast<const float4*>(ip + ic4 * 4);
                acc += wv.x * iv.x + wv.y * iv.y + wv.z * iv.z + wv.w * iv.w;
            }
        }
    }
    if (HASBIAS) acc += bias[oc];
    if (RELU) acc = fmaxf(acc, 0.0f);
    out[(size_t)pix * COUT + oc] = acc;
}

// ---------------------------------------------------------------------------
// Fully-connected, one 64-lane wave per output neuron.
__global__ void fc_wave_kernel(const float* __restrict__ in, const float* __restrict__ w,
                               const float* __restrict__ bias, float* __restrict__ out,
                               int In, int Out, int do_relu) {
    int wid  = (blockIdx.x * blockDim.x + threadIdx.x) >> 6;
    int lane = threadIdx.x & 63;
    if (wid >= BS * Out) return;
    int o = wid % Out;
    int b = wid / Out;
    const float* ip = in + (size_t)b * In;
    const float* wp = w + (size_t)o * In;

    float acc = 0.0f;
    for (int i = lane * 4; i < In; i += 64 * 4) {
        float4 wv = *reinterpret_cast<const float4*>(wp + i);
        float4 iv = *reinterpret_cast<const float4*>(ip + i);
        acc += wv.x * iv.x + wv.y * iv.y + wv.z * iv.z + wv.w * iv.w;
    }
#pragma unroll
    for (int off = 32; off > 0; off >>= 1) acc += __shfl_xor(acc, off, 64);
    if (lane == 0) {
        acc += bias[o];
        if (do_relu) acc = fmaxf(acc, 0.0f);
        out[(size_t)b * Out + o] = acc;
    }
}

// ---------------------------------------------------------------------------
// fusion = relu(gf + lf_nhwc); 1x1 conv -> channel-interleaved grid gt[b][z][y][x][12]
__global__ void fuse_pred_kernel(const float* __restrict__ lf, const float* __restrict__ gfv,
                                 const float* __restrict__ pw, const float* __restrict__ pb,
                                 float* __restrict__ gt) {
    int idx  = blockIdx.x * blockDim.x + threadIdx.x;
    int gid  = idx >> 4;                       // 16 lanes per output
    int lane = idx & 15;
    int total = BS * 96 * 256;
    if (gid >= total) return;
    int sp = gid % 256;
    int oc = (gid / 256) % 96;
    int b  = gid / (256 * 96);

    float4 lv = *reinterpret_cast<const float4*>(lf + ((size_t)(b * 256 + sp) * 64) + lane * 4);
    float4 gv = *reinterpret_cast<const float4*>(gfv + (size_t)b * 64 + lane * 4);
    float4 wv = *reinterpret_cast<const float4*>(pw + (size_t)oc * 64 + lane * 4);
    float fx0 = fmaxf(gv.x + lv.x, 0.0f);
    float fx1 = fmaxf(gv.y + lv.y, 0.0f);
    float fx2 = fmaxf(gv.z + lv.z, 0.0f);
    float fx3 = fmaxf(gv.w + lv.w, 0.0f);
    float acc = wv.x * fx0 + wv.y * fx1 + wv.z * fx2 + wv.w * fx3;
#pragma unroll
    for (int off = 8; off > 0; off >>= 1) acc += __shfl_xor(acc, off, 64);
    if (lane == 0) {
        int z = oc & 7, c12 = oc >> 3;         // pred ch = c12*8 + z
        int y = sp >> 4, x = sp & 15;
        gt[((size_t)b * 2048 + (size_t)(z * 16 + y) * 16 + x) * 12 + c12] = acc + pb[oc];
    }
}

// ---------------------------------------------------------------------------
// Per-pixel: guide curve + trilinear slice (channel-interleaved grid) + affine.
// 4 pixels per thread, float4 I/O.
__global__ void slice4_kernel(const float* __restrict__ hr, const float* __restrict__ gt,
                              const float* __restrict__ pw_mat, const float* __restrict__ pw_bias,
                              const float* __restrict__ pw_bias_tag,
                              const float* __restrict__ rho_a, const float* __restrict__ rho_t,
                              float* __restrict__ out) {
    __shared__ float s_rt[48], s_ra[48], s_m[9], s_bt[3], s_pb;
    int t = threadIdx.x;
    if (t < 48) { s_rt[t] = rho_t[t]; s_ra[t] = rho_a[t]; }
    if (t < 9)  s_m[t] = pw_mat[t];
    if (t < 3)  s_bt[t] = pw_bias_tag[t];
    if (t == 0) s_pb = pw_bias[0];
    __syncthreads();

    const int NXQ = WR / 4;
    int idx = blockIdx.x * blockDim.x + t;
    if (idx >= BS * HR * NXQ) return;
    int xq = idx % NXQ;
    int y  = (idx / NXQ) % HR;
    int b  = idx / (NXQ * HR);
    int x0 = xq * 4;

    const size_t plane = (size_t)HR * WR;
    const float* hp = hr + (size_t)b * 3 * plane + (size_t)y * WR + x0;
    float4 R4 = *reinterpret_cast<const float4*>(hp);
    float4 G4 = *reinterpret_cast<const float4*>(hp + plane);
    float4 B4 = *reinterpret_cast<const float4*>(hp + 2 * plane);
    float rr[4] = {R4.x, R4.y, R4.z, R4.w};
    float gg[4] = {G4.x, G4.y, G4.z, G4.w};
    float bb[4] = {B4.x, B4.y, B4.z, B4.w};

    float gyv = (y + 0.5f) * (16.0f / HR);
    float fyf = fmaxf(floorf(gyv - 0.5f), 0.0f);
    float wyv = gyv - 0.5f - fyf;                 // keeps sign
    int fy = (int)fyf; int cy = min(fy + 1, 15);
    float ey = 1.0f - wyv;

    const float* gbase = gt + (size_t)b * 24576;  // 2048 * 12
    float o0[4], o1[4], o2[4];

#pragma unroll
    for (int j = 0; j < 4; ++j) {
        int x = x0 + j;
        float r = rr[j], g = gg[j], bl = bb[j];

        float g0 = s_m[0] * r + s_m[1] * g + s_m[2] * bl + s_bt[0];
        float g1 = s_m[3] * r + s_m[4] * g + s_m[5] * bl + s_bt[1];
        float g2 = s_m[6] * r + s_m[7] * g + s_m[8] * bl + s_bt[2];
        float guide = s_pb;
#pragma unroll
        for (int k = 0; k < 16; ++k) {
            guide += fmaxf(g0 - s_rt[k * 3 + 0], 0.0f) * s_ra[k * 3 + 0];
            guide += fmaxf(g1 - s_rt[k * 3 + 1], 0.0f) * s_ra[k * 3 + 1];
            guide += fmaxf(g2 - s_rt[k * 3 + 2], 0.0f) * s_ra[k * 3 + 2];
        }

        float gx = (x + 0.5f) * (16.0f / WR);
        float gz = fminf(fmaxf(guide, 0.0f), 1.0f) * 8.0f;
        float fxf = fmaxf(floorf(gx - 0.5f), 0.0f);
        float fzf = fmaxf(floorf(gz - 0.5f), 0.0f);
        float wxv = gx - 0.5f - fxf;              // keeps sign
        float wzv = fabsf(gz - 0.5f - fzf);       // abs
        int fx = (int)fxf; int cx = min(fx + 1, 15);
        int fz = (int)fzf; int cz = min(fz + 1, 7);
        float ex = 1.0f - wxv, ez = 1.0f - wzv;

        int o_ff = (fz * 256 + fy * 16 + fx) * 12;
        int o_cf = (cz * 256 + fy * 16 + fx) * 12;
        int o_fc = (fz * 256 + cy * 16 + fx) * 12;
        int o_cc = (cz * 256 + cy * 16 + fx) * 12;
        int dxo  = (cx - fx) * 12;

        float w_fff = ex * ey * ez, w_cff = ex * ey * wzv;
        float w_fcf = ex * wyv * ez, w_ccf = ex * wyv * wzv;
        float w_ffc = wxv * ey * ez, w_cfc = wxv * ey * wzv;
        float w_fcc = wxv * wyv * ez, w_ccc = wxv * wyv * wzv;

        float4 a0 = {0,0,0,0}, a1 = {0,0,0,0}, a2 = {0,0,0,0};
        const int offs[8] = {o_ff, o_cf, o_fc, o_cc, o_ff + dxo, o_cf + dxo, o_fc + dxo, o_cc + dxo};
        const float wts[8] = {w_fff, w_cff, w_fcf, w_ccf, w_ffc, w_cfc, w_fcc, w_ccc};
#pragma unroll
        for (int c = 0; c < 8; ++c) {
            const float* p = gbase + offs[c];
            float4 v0 = *reinterpret_cast<const float4*>(p);
            float4 v1 = *reinterpret_cast<const float4*>(p + 4);
            float4 v2 = *reinterpret_cast<const float4*>(p + 8);
            float wv = wts[c];
            a0.x += wv * v0.x; a0.y += wv * v0.y; a0.z += wv * v0.z; a0.w += wv * v0.w;
            a1.x += wv * v1.x; a1.y += wv * v1.y; a1.z += wv * v1.z; a1.w += wv * v1.w;
            a2.x += wv * v2.x; a2.y += wv * v2.y; a2.z += wv * v2.z; a2.w += wv * v2.w;
        }
        o0[j] = a0.x * r + a0.y * g + a0.z * bl + a0.w;
        o1[j] = a1.x * r + a1.y * g + a1.z * bl + a1.w;
        o2[j] = a2.x * r + a2.y * g + a2.z * bl + a2.w;
    }

    float* op = out + (size_t)b * 3 * plane + (size_t)y * WR + x0;
    *reinterpret_cast<float4*>(op)              = make_float4(o0[0], o0[1], o0[2], o0[3]);
    *reinterpret_cast<float4*>(op + plane)      = make_float4(o1[0], o1[1], o1[2], o1[3]);
    *reinterpret_cast<float4*>(op + 2 * plane)  = make_float4(o2[0], o2[1], o2[2], o2[3]);
}

extern "C" void kernel_launch(void* const* d_in, const int* in_sizes, int n_in,
                              void* d_out, int out_size, void* d_ws, size_t ws_size,
                              hipStream_t stream) {
    const float* high_res   = (const float*)d_in[0];
    const float* low_res    = (const float*)d_in[1];
    const float* ll1_w = (const float*)d_in[2];  const float* ll1_b = (const float*)d_in[3];
    const float* ll2_w = (const float*)d_in[4];  const float* ll2_b = (const float*)d_in[5];
    const float* ll3_w = (const float*)d_in[6];  const float* ll3_b = (const float*)d_in[7];
    const float* ll4_w = (const float*)d_in[8];  const float* ll4_b = (const float*)d_in[9];
    const float* lf1_w = (const float*)d_in[10]; const float* lf1_b = (const float*)d_in[11];
    const float* lf2_w = (const float*)d_in[12];
    const float* gf1_w = (const float*)d_in[13]; const float* gf1_b = (const float*)d_in[14];
    const float* gf2_w = (const float*)d_in[15]; const float* gf2_b = (const float*)d_in[16];
    const float* fc1_w = (const float*)d_in[17]; const float* fc1_b = (const float*)d_in[18];
    const float* fc2_w = (const float*)d_in[19]; const float* fc2_b = (const float*)d_in[20];
    const float* fc3_w = (const float*)d_in[21]; const float* fc3_b = (const float*)d_in[22];
    const float* pred_w = (const float*)d_in[23]; const float* pred_b = (const float*)d_in[24];
    const float* pw_mat = (const float*)d_in[25];
    const float* pw_bias = (const float*)d_in[26];
    const float* pw_bias_tag = (const float*)d_in[27];
    const float* rho_a = (const float*)d_in[28];
    const float* rho_t = (const float*)d_in[29];

    float* ws = (float*)d_ws;
    // NHWC activations
    float* b1    = ws;                  // (2,128,128,8)  262144
    float* b2    = b1 + 262144;         // (2,64,64,16)   131072
    float* b3    = b2 + 131072;         // (2,32,32,32)    65536
    float* b4    = b3 + 65536;          // (2,16,16,64)    32768
    float* lf1o  = b4 + 32768;          // (2,16,16,64)    32768
    float* lf2o  = lf1o + 32768;        // (2,16,16,64)    32768
    float* gf1o  = lf2o + 32768;        // (2,8,8,64)       8192
    float* gf2o  = gf1o + 8192;         // (2,4,4,64)       2048
    float* fc1o  = gf2o + 2048;         // (2,256)           512
    float* fc2o  = fc1o + 512;          // (2,128)           256
    float* fc3o  = fc2o + 256;          // (2,64)            128
    float* gt    = fc3o + 128;          // (2,2048,12)     49152
    // repacked weights
    float* wll2T = gt + 49152;          //  1152
    float* wll3T = wll2T + 1152;        //  4608
    float* wll4T = wll3T + 4608;        // 18432
    float* wlf1T = wll4T + 18432;       // 36864
    float* wlf2T = wlf1T + 36864;       // 36864
    float* wgf1T = wlf2T + 36864;       // 36864
    float* wgf2T = wgf1T + 36864;       // 36864
    float* wfc1T = wgf2T + 36864;       // 262144

    float* out = (float*)d_out;
    dim3 blk(256);

    // weight repack (conv wT + fc1 permute)
    repack_kernel<<<cdiv(171648 + 262144, 256), blk, 0, stream>>>(
        ll2_w, ll3_w, ll4_w, lf1_w, lf2_w, gf1_w, gf2_w,
        wll2T, wll3T, wll4T, wlf1T, wlf2T, wgf1T, wgf2T,
        fc1_w, wfc1T);

    // low-res CNN trunk (NHWC)
    ll1_nhwc_kernel<<<cdiv(BS*128*128, 256), blk, 0, stream>>>(low_res, ll1_w, ll1_b, b1);
    conv_nhwc_kernel<16, 8, true, true><<<cdiv(BS*64*64*16, 256), blk, 0, stream>>>(b1, wll2T, ll2_b, b2, 128, 128, 64, 64, 2);
    conv_nhwc_kernel<32, 16, true, true><<<cdiv(BS*32*32*32, 256), blk, 0, stream>>>(b2, wll3T, ll3_b, b3, 64, 64, 32, 32, 2);
    conv_nhwc_kernel<64, 32, true, true><<<cdiv(BS*16*16*64, 256), blk, 0, stream>>>(b3, wll4T, ll4_b, b4, 32, 32, 16, 16, 2);
    // local features
    conv_nhwc_kernel<64, 64, true, true><<<cdiv(BS*16*16*64, 256), blk, 0, stream>>>(b4, wlf1T, lf1_b, lf1o, 16, 16, 16, 16, 1);
    conv_nhwc_kernel<64, 64, false, false><<<cdiv(BS*16*16*64, 256), blk, 0, stream>>>(lf1o, wlf2T, nullptr, lf2o, 16, 16, 16, 16, 1);
    // global features
    conv_nhwc_kernel<64, 64, true, true><<<cdiv(BS*8*8*64, 256), blk, 0, stream>>>(b4, wgf1T, gf1_b, gf1o, 16, 16, 8, 8, 2);
    conv_nhwc_kernel<64, 64, true, true><<<cdiv(BS*4*4*64, 256), blk, 0, stream>>>(gf1o, wgf2T, gf2_b, gf2o, 8, 8, 4, 4, 2);
    // FC stack (fc1 uses NHWC-permuted weights)
    fc_wave_kernel<<<cdiv(BS*256*64, 256), blk, 0, stream>>>(gf2o, wfc1T, fc1_b, fc1o, 1024, 256, 1);
    fc_wave_kernel<<<cdiv(BS*128*64, 256), blk, 0, stream>>>(fc1o, fc2_w, fc2_b, fc2o, 256, 128, 1);
    fc_wave_kernel<<<cdiv(BS*64*64, 256),  blk, 0, stream>>>(fc2o, fc3_w, fc3_b, fc3o, 128, 64, 0);
    // fusion + pred -> channel-interleaved grid
    fuse_pred_kernel<<<cdiv(BS*96*256*16, 256), blk, 0, stream>>>(lf2o, fc3o, pred_w, pred_b, gt);
    // per-pixel guide + slice + assemble (4 px/thread)
    slice4_kernel<<<cdiv(BS*HR*WR/4, 256), blk, 0, stream>>>(high_res, gt, pw_mat, pw_bias, pw_bias_tag,
                                                             rho_a, rho_t, out);
}

// Round 6
// 97.367 us; speedup vs baseline: 5.8223x; 1.3360x over previous
//
#include <hip/hip_runtime.h>

#define BS 2
#define HR 1024
#define WR 1024

static inline int cdiv(int a, int b) { return (a + b - 1) / b; }

// ---------------------------------------------------------------------------
// Weight repack (one launch, fully parallel):
//  - 7 conv layers:  w[oc][ic][ky][kx]  ->  wT[k][oc][ic]   (ic contiguous)
//  - fc1:            w[o][c*16+s]       ->  wT[o][s*64+c]   (NCHW->NHWC flatten)
__global__ void repack_kernel(const float* __restrict__ s0, const float* __restrict__ s1,
                              const float* __restrict__ s2, const float* __restrict__ s3,
                              const float* __restrict__ s4, const float* __restrict__ s5,
                              const float* __restrict__ s6,
                              float* __restrict__ d0, float* __restrict__ d1,
                              float* __restrict__ d2, float* __restrict__ d3,
                              float* __restrict__ d4, float* __restrict__ d5,
                              float* __restrict__ d6,
                              const float* __restrict__ fcs, float* __restrict__ fcd) {
    const int CONV_TOTAL = 171648;           // sum of cout*cin*9
    int idx = blockIdx.x * blockDim.x + threadIdx.x;
    if (idx < CONV_TOTAL) {
        const float* src[7] = {s0, s1, s2, s3, s4, s5, s6};
        float* dst[7]       = {d0, d1, d2, d3, d4, d5, d6};
        const int cout[7] = {16, 32, 64, 64, 64, 64, 64};
        const int cin[7]  = {8, 16, 32, 64, 64, 64, 64};
        const int sz[7]   = {1152, 4608, 18432, 36864, 36864, 36864, 36864};
        int l = 0, e = idx;
        while (e >= sz[l]) { e -= sz[l]; ++l; }
        int Cin = cin[l], Cout = cout[l];
        int oc = e / (Cin * 9);
        int rem = e - oc * Cin * 9;
        int ic = rem / 9;
        int k  = rem - ic * 9;
        dst[l][((size_t)(k * Cout + oc)) * Cin + ic] = src[l][e];
    } else {
        int e = idx - CONV_TOTAL;            // fc1: 256*1024 = 262144 elements
        if (e >= 262144) return;
        int o = e >> 10, j = e & 1023;
        int s = j >> 6, c = j & 63;
        fcd[e] = fcs[(o << 10) + (c << 4) + s];
    }
}

// ---------------------------------------------------------------------------
// ll1: NCHW input (2,3,256,256), stride 2, pad 1 -> NHWC output (2,128,128,8).
__global__ void ll1_nhwc_kernel(const float* __restrict__ in, const float* __restrict__ w,
                                const float* __restrict__ bias, float* __restrict__ out) {
    int idx = blockIdx.x * blockDim.x + threadIdx.x;
    if (idx >= BS * 128 * 128) return;
    int ox = idx & 127;
    int oy = (idx >> 7) & 127;
    int b  = idx >> 14;

    float acc[8];
#pragma unroll
    for (int oc = 0; oc < 8; ++oc) acc[oc] = bias[oc];

#pragma unroll
    for (int ky = 0; ky < 3; ++ky) {
        int iy = 2 * oy - 1 + ky;
        if (iy < 0 || iy >= 256) continue;
#pragma unroll
        for (int kx = 0; kx < 3; ++kx) {
            int ix = 2 * ox - 1 + kx;
            if (ix < 0 || ix >= 256) continue;
#pragma unroll
            for (int ic = 0; ic < 3; ++ic) {
                float v = in[(((size_t)b * 3 + ic) * 256 + iy) * 256 + ix];
#pragma unroll
                for (int oc = 0; oc < 8; ++oc)
                    acc[oc] += w[oc * 27 + ic * 9 + ky * 3 + kx] * v;
            }
        }
    }
    float* op = out + (size_t)idx * 8;
#pragma unroll
    for (int oc = 0; oc < 8; ++oc) op[oc] = fmaxf(acc[oc], 0.0f);
}

// ---------------------------------------------------------------------------
// NHWC conv3x3 pad=1, G-way input-channel split. lane = (oc, icg):
// weight f4 loads coalesced from wT[k][oc][ic]; input f4 lane-group-uniform;
// shfl_xor reduce over icg; lanes icg==0 write coalesced COUT-contiguous out.
template <int COUT, int CIN, int G, bool RELU, bool HASBIAS>
__global__ void conv_nhwc_split(const float* __restrict__ in, const float* __restrict__ wT,
                                const float* __restrict__ bias, float* __restrict__ out,
                                int Hin, int Win, int Hout, int Wout, int stride) {
    constexpr int ICPG = CIN / G;            // ic per group (multiple of 4)
    int idx = blockIdx.x * blockDim.x + threadIdx.x;
    int total = BS * Hout * Wout * COUT * G;
    if (idx >= total) return;
    int icg = idx & (G - 1);
    int oc  = (idx / G) & (COUT - 1);
    int pix = idx / (G * COUT);
    int ox = pix % Wout;
    int oy = (pix / Wout) % Hout;
    int b  = pix / (Wout * Hout);

    int iy0 = oy * stride - 1;
    int ix0 = ox * stride - 1;
    float acc = 0.0f;
#pragma unroll
    for (int ky = 0; ky < 3; ++ky) {
        int iy = iy0 + ky;
        if (iy < 0 || iy >= Hin) continue;
#pragma unroll
        for (int kx = 0; kx < 3; ++kx) {
            int ix = ix0 + kx;
            if (ix < 0 || ix >= Win) continue;
            int k = ky * 3 + kx;
            const float* wp = wT + ((size_t)(k * COUT + oc)) * CIN + icg * ICPG;
            const float* ip = in + ((size_t)((b * Hin + iy) * Win + ix)) * CIN + icg * ICPG;
#pragma unroll
            for (int ic4 = 0; ic4 < ICPG / 4; ++ic4) {
                float4 wv = *reinterpret_cast<const float4*>(wp + ic4 * 4);
                float4 iv = *reinterpret_cast<const float4*>(ip + ic4 * 4);
                acc += wv.x * iv.x + wv.y * iv.y + wv.z * iv.z + wv.w * iv.w;
            }
        }
    }
    if (G > 1) {
#pragma unroll
        for (int off = G / 2; off > 0; off >>= 1) acc += __shfl_xor(acc, off, 64);
    }
    if (icg == 0) {
        if (HASBIAS) acc += bias[oc];
        if (RELU) acc = fmaxf(acc, 0.0f);
        out[(size_t)pix * COUT + oc] = acc;
    }
}

// ---------------------------------------------------------------------------
// Fully-connected, one 64-lane wave per output neuron.
__global__ void fc_wave_kernel(const float* __restrict__ in, const float* __restrict__ w,
                               const float* __restrict__ bias, float* __restrict__ out,
                               int In, int Out, int do_relu) {
    int wid  = (blockIdx.x * blockDim.x + threadIdx.x) >> 6;
    int lane = threadIdx.x & 63;
    if (wid >= BS * Out) return;
    int o = wid % Out;
    int b = wid / Out;
    const float* ip = in + (size_t)b * In;
    const float* wp = w + (size_t)o * In;

    float acc = 0.0f;
    for (int i = lane * 4; i < In; i += 64 * 4) {
        float4 wv = *reinterpret_cast<const float4*>(wp + i);
        float4 iv = *reinterpret_cast<const float4*>(ip + i);
        acc += wv.x * iv.x + wv.y * iv.y + wv.z * iv.z + wv.w * iv.w;
    }
#pragma unroll
    for (int off = 32; off > 0; off >>= 1) acc += __shfl_xor(acc, off, 64);
    if (lane == 0) {
        acc += bias[o];
        if (do_relu) acc = fmaxf(acc, 0.0f);
        out[(size_t)b * Out + o] = acc;
    }
}

// ---------------------------------------------------------------------------
// fusion = relu(gf + lf_nhwc); 1x1 conv -> channel-interleaved grid gt[b][z][y][x][12]
__global__ void fuse_pred_kernel(const float* __restrict__ lf, const float* __restrict__ gfv,
                                 const float* __restrict__ pw, const float* __restrict__ pb,
                                 float* __restrict__ gt) {
    int idx  = blockIdx.x * blockDim.x + threadIdx.x;
    int gid  = idx >> 4;                       // 16 lanes per output
    int lane = idx & 15;
    int total = BS * 96 * 256;
    if (gid >= total) return;
    int sp = gid % 256;
    int oc = (gid / 256) % 96;
    int b  = gid / (256 * 96);

    float4 lv = *reinterpret_cast<const float4*>(lf + ((size_t)(b * 256 + sp) * 64) + lane * 4);
    float4 gv = *reinterpret_cast<const float4*>(gfv + (size_t)b * 64 + lane * 4);
    float4 wv = *reinterpret_cast<const float4*>(pw + (size_t)oc * 64 + lane * 4);
    float fx0 = fmaxf(gv.x + lv.x, 0.0f);
    float fx1 = fmaxf(gv.y + lv.y, 0.0f);
    float fx2 = fmaxf(gv.z + lv.z, 0.0f);
    float fx3 = fmaxf(gv.w + lv.w, 0.0f);
    float acc = wv.x * fx0 + wv.y * fx1 + wv.z * fx2 + wv.w * fx3;
#pragma unroll
    for (int off = 8; off > 0; off >>= 1) acc += __shfl_xor(acc, off, 64);
    if (lane == 0) {
        int z = oc & 7, c12 = oc >> 3;         // pred ch = c12*8 + z
        int y = sp >> 4, x = sp & 15;
        gt[((size_t)b * 2048 + (size_t)(z * 16 + y) * 16 + x) * 12 + c12] = acc + pb[oc];
    }
}

// ---------------------------------------------------------------------------
// Slice: one block per image row. Stage the row's (fy,cy) slab of the grid
// (8z x 2y x 16x x 12c = 12KB) into LDS; per-pixel gathers become ds_read_b128.
// 4 px/thread, float4 I/O. slab layout: [z][yy][x][12] -> z*384 + yy*192 + x*12 + c.
__global__ void slice_row_kernel(const float* __restrict__ hr, const float* __restrict__ gt,
                                 const float* __restrict__ pw_mat, const float* __restrict__ pw_bias,
                                 const float* __restrict__ pw_bias_tag,
                                 const float* __restrict__ rho_a, const float* __restrict__ rho_t,
                                 float* __restrict__ out) {
    __shared__ float slab[3072];
    __shared__ float s_rt[48], s_ra[48], s_m[9], s_bt[3], s_pb;
    int t = threadIdx.x;
    int y = blockIdx.x & (HR - 1);
    int b = blockIdx.x >> 10;

    // y-interp (uniform over the row)
    float gyv = (y + 0.5f) * (16.0f / HR);
    float fyf = fmaxf(floorf(gyv - 0.5f), 0.0f);
    float wyv = gyv - 0.5f - fyf;                 // keeps sign (torch semantics)
    int fy = (int)fyf; int cy = min(fy + 1, 15);
    float ey = 1.0f - wyv;

    if (t < 48) { s_rt[t] = rho_t[t]; s_ra[t] = rho_a[t]; }
    if (t < 9)  s_m[t] = pw_mat[t];
    if (t < 3)  s_bt[t] = pw_bias_tag[t];
    if (t == 0) s_pb = pw_bias[0];

    // stage slab: 768 f4, 3 per thread, coalesced within (z,yy) runs
    const float* gb = gt + (size_t)b * 24576;
#pragma unroll
    for (int k = 0; k < 3; ++k) {
        int s = (t + k * 256) * 4;
        int zz  = s / 384;
        int rem = s - zz * 384;
        int yy  = rem / 192;
        int rc  = rem - yy * 192;                 // x*12 + c, f4-aligned
        int ysrc = yy ? cy : fy;
        *reinterpret_cast<float4*>(slab + s) =
            *reinterpret_cast<const float4*>(gb + (size_t)(zz * 16 + ysrc) * 192 + rc);
    }
    __syncthreads();

    const size_t plane = (size_t)HR * WR;
    int x0 = t * 4;
    const float* hp = hr + (size_t)b * 3 * plane + (size_t)y * WR + x0;
    float4 R4 = *reinterpret_cast<const float4*>(hp);
    float4 G4 = *reinterpret_cast<const float4*>(hp + plane);
    float4 B4 = *reinterpret_cast<const float4*>(hp + 2 * plane);
    float rr[4] = {R4.x, R4.y, R4.z, R4.w};
    float gg[4] = {G4.x, G4.y, G4.z, G4.w};
    float bb[4] = {B4.x, B4.y, B4.z, B4.w};

    float o0[4], o1[4], o2[4];
#pragma unroll
    for (int j = 0; j < 4; ++j) {
        int x = x0 + j;
        float r = rr[j], g = gg[j], bl = bb[j];

        float g0 = s_m[0] * r + s_m[1] * g + s_m[2] * bl + s_bt[0];
        float g1 = s_m[3] * r + s_m[4] * g + s_m[5] * bl + s_bt[1];
        float g2 = s_m[6] * r + s_m[7] * g + s_m[8] * bl + s_bt[2];
        float guide = s_pb;
#pragma unroll
        for (int k = 0; k < 16; ++k) {
            guide += fmaxf(g0 - s_rt[k * 3 + 0], 0.0f) * s_ra[k * 3 + 0];
            guide += fmaxf(g1 - s_rt[k * 3 + 1], 0.0f) * s_ra[k * 3 + 1];
            guide += fmaxf(g2 - s_rt[k * 3 + 2], 0.0f) * s_ra[k * 3 + 2];
        }

        float gx = (x + 0.5f) * (16.0f / WR);
        float gz = fminf(fmaxf(guide, 0.0f), 1.0f) * 8.0f;
        float fxf = fmaxf(floorf(gx - 0.5f), 0.0f);
        float fzf = fmaxf(floorf(gz - 0.5f), 0.0f);
        float wxv = gx - 0.5f - fxf;              // keeps sign
        float wzv = fabsf(gz - 0.5f - fzf);       // abs (torch semantics)
        int fx = (int)fxf; int cx = min(fx + 1, 15);
        int fz = (int)fzf; int cz = min(fz + 1, 7);
        float ex = 1.0f - wxv, ez = 1.0f - wzv;

        // slab offsets: z*384 + yy*192 + x*12
        int o_ff = fz * 384 + fx * 12;            // (fz, fy)
        int o_cf = cz * 384 + fx * 12;            // (cz, fy)
        int o_fc = o_ff + 192;                    // (fz, cy)
        int o_cc = o_cf + 192;                    // (cz, cy)
        int dxo  = (cx - fx) * 12;

        float w_fff = ex * ey * ez, w_cff = ex * ey * wzv;
        float w_fcf = ex * wyv * ez, w_ccf = ex * wyv * wzv;
        float w_ffc = wxv * ey * ez, w_cfc = wxv * ey * wzv;
        float w_fcc = wxv * wyv * ez, w_ccc = wxv * wyv * wzv;

        float4 a0 = {0,0,0,0}, a1 = {0,0,0,0}, a2 = {0,0,0,0};
        const int offs[8] = {o_ff, o_cf, o_fc, o_cc, o_ff + dxo, o_cf + dxo, o_fc + dxo, o_cc + dxo};
        const float wts[8] = {w_fff, w_cff, w_fcf, w_ccf, w_ffc, w_cfc, w_fcc, w_ccc};
#pragma unroll
        for (int c = 0; c < 8; ++c) {
            const float* p = slab + offs[c];
            float4 v0 = *reinterpret_cast<const float4*>(p);
            float4 v1 = *reinterpret_cast<const float4*>(p + 4);
            float4 v2 = *reinterpret_cast<const float4*>(p + 8);
            float wv = wts[c];
            a0.x += wv * v0.x; a0.y += wv * v0.y; a0.z += wv * v0.z; a0.w += wv * v0.w;
            a1.x += wv * v1.x; a1.y += wv * v1.y; a1.z += wv * v1.z; a1.w += wv * v1.w;
            a2.x += wv * v2.x; a2.y += wv * v2.y; a2.z += wv * v2.z; a2.w += wv * v2.w;
        }
        o0[j] = a0.x * r + a0.y * g + a0.z * bl + a0.w;
        o1[j] = a1.x * r + a1.y * g + a1.z * bl + a1.w;
        o2[j] = a2.x * r + a2.y * g + a2.z * bl + a2.w;
    }

    float* op = out + (size_t)b * 3 * plane + (size_t)y * WR + x0;
    *reinterpret_cast<float4*>(op)              = make_float4(o0[0], o0[1], o0[2], o0[3]);
    *reinterpret_cast<float4*>(op + plane)      = make_float4(o1[0], o1[1], o1[2], o1[3]);
    *reinterpret_cast<float4*>(op + 2 * plane)  = make_float4(o2[0], o2[1], o2[2], o2[3]);
}

extern "C" void kernel_launch(void* const* d_in, const int* in_sizes, int n_in,
                              void* d_out, int out_size, void* d_ws, size_t ws_size,
                              hipStream_t stream) {
    const float* high_res   = (const float*)d_in[0];
    const float* low_res    = (const float*)d_in[1];
    const float* ll1_w = (const float*)d_in[2];  const float* ll1_b = (const float*)d_in[3];
    const float* ll2_w = (const float*)d_in[4];  const float* ll2_b = (const float*)d_in[5];
    const float* ll3_w = (const float*)d_in[6];  const float* ll3_b = (const float*)d_in[7];
    const float* ll4_w = (const float*)d_in[8];  const float* ll4_b = (const float*)d_in[9];
    const float* lf1_w = (const float*)d_in[10]; const float* lf1_b = (const float*)d_in[11];
    const float* lf2_w = (const float*)d_in[12];
    const float* gf1_w = (const float*)d_in[13]; const float* gf1_b = (const float*)d_in[14];
    const float* gf2_w = (const float*)d_in[15]; const float* gf2_b = (const float*)d_in[16];
    const float* fc1_w = (const float*)d_in[17]; const float* fc1_b = (const float*)d_in[18];
    const float* fc2_w = (const float*)d_in[19]; const float* fc2_b = (const float*)d_in[20];
    const float* fc3_w = (const float*)d_in[21]; const float* fc3_b = (const float*)d_in[22];
    const float* pred_w = (const float*)d_in[23]; const float* pred_b = (const float*)d_in[24];
    const float* pw_mat = (const float*)d_in[25];
    const float* pw_bias = (const float*)d_in[26];
    const float* pw_bias_tag = (const float*)d_in[27];
    const float* rho_a = (const float*)d_in[28];
    const float* rho_t = (const float*)d_in[29];

    float* ws = (float*)d_ws;
    // NHWC activations
    float* b1    = ws;                  // (2,128,128,8)  262144
    float* b2    = b1 + 262144;         // (2,64,64,16)   131072
    float* b3    = b2 + 131072;         // (2,32,32,32)    65536
    float* b4    = b3 + 65536;          // (2,16,16,64)    32768
    float* lf1o  = b4 + 32768;          // (2,16,16,64)    32768
    float* lf2o  = lf1o + 32768;        // (2,16,16,64)    32768
    float* gf1o  = lf2o + 32768;        // (2,8,8,64)       8192
    float* gf2o  = gf1o + 8192;         // (2,4,4,64)       2048
    float* fc1o  = gf2o + 2048;         // (2,256)           512
    float* fc2o  = fc1o + 512;          // (2,128)           256
    float* fc3o  = fc2o + 256;          // (2,64)            128
    float* gt    = fc3o + 128;          // (2,2048,12)     49152
    // repacked weights [k][oc][ic]
    float* wll2T = gt + 49152;          //  1152
    float* wll3T = wll2T + 1152;        //  4608
    float* wll4T = wll3T + 4608;        // 18432
    float* wlf1T = wll4T + 18432;       // 36864
    float* wlf2T = wlf1T + 36864;       // 36864
    float* wgf1T = wlf2T + 36864;       // 36864
    float* wgf2T = wgf1T + 36864;       // 36864
    float* wfc1T = wgf2T + 36864;       // 262144

    float* out = (float*)d_out;
    dim3 blk(256);

    // weight repack (conv wT + fc1 permute)
    repack_kernel<<<cdiv(171648 + 262144, 256), blk, 0, stream>>>(
        ll2_w, ll3_w, ll4_w, lf1_w, lf2_w, gf1_w, gf2_w,
        wll2T, wll3T, wll4T, wlf1T, wlf2T, wgf1T, wgf2T,
        fc1_w, wfc1T);

    // low-res CNN trunk (NHWC, ic-split for deep layers)
    ll1_nhwc_kernel<<<cdiv(BS*128*128, 256), blk, 0, stream>>>(low_res, ll1_w, ll1_b, b1);
    conv_nhwc_split<16, 8, 1, true, true><<<cdiv(BS*64*64*16, 256), blk, 0, stream>>>(b1, wll2T, ll2_b, b2, 128, 128, 64, 64, 2);
    conv_nhwc_split<32, 16, 1, true, true><<<cdiv(BS*32*32*32, 256), blk, 0, stream>>>(b2, wll3T, ll3_b, b3, 64, 64, 32, 32, 2);
    conv_nhwc_split<64, 32, 2, true, true><<<cdiv(BS*16*16*64*2, 256), blk, 0, stream>>>(b3, wll4T, ll4_b, b4, 32, 32, 16, 16, 2);
    // local features
    conv_nhwc_split<64, 64, 4, true, true><<<cdiv(BS*16*16*64*4, 256), blk, 0, stream>>>(b4, wlf1T, lf1_b, lf1o, 16, 16, 16, 16, 1);
    conv_nhwc_split<64, 64, 4, false, false><<<cdiv(BS*16*16*64*4, 256), blk, 0, stream>>>(lf1o, wlf2T, nullptr, lf2o, 16, 16, 16, 16, 1);
    // global features
    conv_nhwc_split<64, 64, 4, true, true><<<cdiv(BS*8*8*64*4, 256), blk, 0, stream>>>(b4, wgf1T, gf1_b, gf1o, 16, 16, 8, 8, 2);
    conv_nhwc_split<64, 64, 4, true, true><<<cdiv(BS*4*4*64*4, 256), blk, 0, stream>>>(gf1o, wgf2T, gf2_b, gf2o, 8, 8, 4, 4, 2);
    // FC stack (fc1 uses NHWC-permuted weights)
    fc_wave_kernel<<<cdiv(BS*256*64, 256), blk, 0, stream>>>(gf2o, wfc1T, fc1_b, fc1o, 1024, 256, 1);
    fc_wave_kernel<<<cdiv(BS*128*64, 256), blk, 0, stream>>>(fc1o, fc2_w, fc2_b, fc2o, 256, 128, 1);
    fc_wave_kernel<<<cdiv(BS*64*64, 256),  blk, 0, stream>>>(fc2o, fc3_w, fc3_b, fc3o, 128, 64, 0);
    // fusion + pred -> channel-interleaved grid
    fuse_pred_kernel<<<cdiv(BS*96*256*16, 256), blk, 0, stream>>>(lf2o, fc3o, pred_w, pred_b, gt);
    // per-row slice: LDS slab + guide + trilinear + affine (4 px/thread)
    slice_row_kernel<<<BS*HR, blk, 0, stream>>>(high_res, gt, pw_mat, pw_bias, pw_bias_tag,
                                                rho_a, rho_t, out);
}